// Round 15
// baseline (909.188 us; speedup 1.0000x reference)
//
#include <hip/hip_runtime.h>
#include <math.h>

// Problem constants
#define B_  2
#define S_  2048
#define D_  2048
#define H_  16
#define HD_ 128

using u16 = unsigned short;
using u32 = unsigned int;
typedef __attribute__((ext_vector_type(4))) float f32x4;
typedef __attribute__((ext_vector_type(8))) short bf16x8;   // 8 bf16 = 4 VGPRs (MFMA A/B frag)
using u16x4_t = __attribute__((ext_vector_type(4))) unsigned short;
using u16x8_t = __attribute__((ext_vector_type(8))) unsigned short;
typedef __attribute__((ext_vector_type(2))) u32 u32x2;
typedef __attribute__((ext_vector_type(4))) u32 u32x4;

__device__ __forceinline__ u16 f2bf(float f) {
  u32 u = __builtin_bit_cast(u32, f);
  u32 r = u + 0x7fffu + ((u >> 16) & 1u);   // RNE
  return (u16)(r >> 16);
}
__device__ __forceinline__ float bf2f(u16 x) {
  u32 u = ((u32)x) << 16;
  return __builtin_bit_cast(float, u);
}
// async global->LDS, 16B per lane; LDS dest = wave-uniform base + lane*16;
// global source address is PER-LANE (enables source-side swizzling).
__device__ __forceinline__ void async_copy16(const u16* g, u16* l) {
  __builtin_amdgcn_global_load_lds((const __attribute__((address_space(1))) u32*)g,
                                   (__attribute__((address_space(3))) u32*)l, 16, 0, 0);
}

// ---------------- fused fp32 -> bf16 convert (x, Wq, Wk, Wv, Wo in one pass) ----------------
__global__ void cvt_all(const float* __restrict__ x, const float* __restrict__ Wq,
                        const float* __restrict__ Wk, const float* __restrict__ Wv,
                        const float* __restrict__ Wo, u16* __restrict__ dst) {
  const int i = (blockIdx.x * blockDim.x + threadIdx.x) * 4;
  if (i >= 25165824) return;
  const float* src;
  int off;
  if (i < (1 << 23)) { src = x; off = i; }
  else {
    const int wi = i - (1 << 23);
    const int which = wi >> 22;
    off = wi & ((1 << 22) - 1);
    src = (which == 0) ? Wq : (which == 1) ? Wk : (which == 2) ? Wv : Wo;
  }
  float4 v = *(const float4*)(src + off);
  u16x4_t o;
  o[0] = f2bf(v.x); o[1] = f2bf(v.y); o[2] = f2bf(v.z); o[3] = f2bf(v.w);
  *(u16x4_t*)(dst + i) = o;
}

// ---------------- RoPE cos/sin table ----------------
__global__ void rope_table(const int* __restrict__ pos, float2* __restrict__ tab) {
  int t = blockIdx.x * blockDim.x + threadIdx.x;  // S*64
  if (t >= S_ * 64) return;
  int s = t >> 6, i = t & 63;
  float freq = expf(-(float)i * (9.210340371976184f / 64.0f));  // theta^{-i/64}
  float ang = (float)pos[s] * freq;
  tab[t] = make_float2(cosf(ang), sinf(ang));
}

// ---------------- K-only RoPE (proven standalone) ----------------
__global__ void rope_k(u16* __restrict__ K, const float2* __restrict__ tab) {
  int t = blockIdx.x * blockDim.x + threadIdx.x;  // B*S*H*16
  int g = t & 15;
  int bsh = t >> 4;
  int h = bsh & (H_ - 1);
  int bs = bsh >> 4;            // b*S + s
  int s = bs & (S_ - 1);
  size_t base = (size_t)bs * D_ + (size_t)h * HD_;
  int d2 = g * 4;
  const float2* tb = &tab[s * 64 + d2];
  float2 cs[4];
  #pragma unroll
  for (int j = 0; j < 4; ++j) cs[j] = tb[j];
  u16x4_t a = *(u16x4_t*)(K + base + d2);
  u16x4_t c = *(u16x4_t*)(K + base + 64 + d2);
  u16x4_t ra, rc;
  #pragma unroll
  for (int j = 0; j < 4; ++j) {
    float t1 = bf2f(a[j]), t2 = bf2f(c[j]);
    ra[j] = f2bf(t1 * cs[j].x - t2 * cs[j].y);
    rc[j] = f2bf(t1 * cs[j].y + t2 * cs[j].x);
  }
  *(u16x4_t*)(K + base + d2) = ra;
  *(u16x4_t*)(K + base + 64 + d2) = rc;
}

// ---------------- GEMM: C = A(MxK) * Bt(NxK)^T (128x128, round-10 proven) ----------------
template <bool F32OUT>
__global__ void gemm_bt(const u16* __restrict__ A, const u16* __restrict__ Bt,
                        void* __restrict__ Cout, int M, int N, int K) {
  __shared__ u16 lA[3][128 * 32];
  __shared__ u16 lB[3][128 * 32];
  const int tid = threadIdx.x;
  const int lane = tid & 63;
  const int w = tid >> 6;            // wave 0..3
  const int wr = w >> 1, wc = w & 1; // 2x2 waves of 64x64
  const int bm = blockIdx.x * 128;
  const int bn = blockIdx.y * 128;
  const int fr = lane & 15, fq = lane >> 4;
  const int KT = K >> 5;
  f32x4 acc[4][4] = {};

  auto stage = [&](int buf, int kt) {
    const int k0 = kt << 5;
    #pragma unroll
    for (int c = w; c < 8; c += 4) {
      const int r = c * 16 + (lane >> 2);
      const int col = ((lane & 3) ^ ((r >> 1) & 3)) * 8;   // pre-swizzled source slot
      async_copy16(A + (size_t)(bm + r) * K + k0 + col, &lA[buf][c * 512]);
      async_copy16(Bt + (size_t)(bn + r) * K + k0 + col, &lB[buf][c * 512]);
    }
  };

  stage(0, 0);
  stage(1, 1);
  asm volatile("s_waitcnt vmcnt(4)" ::: "memory");   // tile 0 landed; tile 1 in flight
  __builtin_amdgcn_s_barrier();
  asm volatile("" ::: "memory");

  int p = 0, sb = 2;
  #pragma unroll 1
  for (int kt = 0; kt < KT; ++kt) {
    if (kt + 2 < KT) stage(sb, kt + 2);
    bf16x8 af[4], bfr[4];
    #pragma unroll
    for (int i = 0; i < 4; ++i) {
      const int ra = wr * 64 + i * 16 + fr;
      const int rb = wc * 64 + i * 16 + fr;
      af[i]  = *(const bf16x8*)&lA[p][ra * 32 + ((fq ^ ((ra >> 1) & 3)) * 8)];
      bfr[i] = *(const bf16x8*)&lB[p][rb * 32 + ((fq ^ ((rb >> 1) & 3)) * 8)];
    }
    #pragma unroll
    for (int i = 0; i < 4; ++i)
      #pragma unroll
      for (int j = 0; j < 4; ++j)
        acc[i][j] = __builtin_amdgcn_mfma_f32_16x16x32_bf16(af[i], bfr[j], acc[i][j], 0, 0, 0);
    if (kt + 1 < KT) {
      if (kt + 2 < KT) asm volatile("s_waitcnt vmcnt(4)" ::: "memory");  // kt+1 landed
      else             asm volatile("s_waitcnt vmcnt(0)" ::: "memory");  // tail drain
      __builtin_amdgcn_s_barrier();
      asm volatile("" ::: "memory");
    }
    p  = (p == 2) ? 0 : p + 1;
    sb = (sb == 2) ? 0 : sb + 1;
  }
  // C/D layout: col = lane&15, row = (lane>>4)*4 + reg  [m89/m91 verified]
  #pragma unroll
  for (int i = 0; i < 4; ++i)
    #pragma unroll
    for (int j = 0; j < 4; ++j) {
      const int row = bm + wr * 64 + i * 16 + fq * 4;
      const int col = bn + wc * 64 + j * 16 + fr;
      #pragma unroll
      for (int r = 0; r < 4; ++r) {
        const float v = acc[i][j][r];
        if (F32OUT) ((float*)Cout)[(size_t)(row + r) * N + col] = v;
        else        ((u16*)Cout)[(size_t)(row + r) * N + col] = f2bf(v);
      }
    }
}

// ---------------- fused QKV GEMM, 128x256 tile / 4 waves / 128x64 per wave ----------------
// Round-15: same proven sync structure as r10 (triple-buffer, counted vmcnt, 1 raw
// barrier/K-step, both-sides slot swizzle) with doubled per-wave MFMA:overhead
// ratio: 32 MFMA / 12 ds_read per K-step (was 16/8). Grid (32,24)=768 = exactly
// 3 blocks/CU (uniform); LDS 72KB -> 2 resident; acc[8][4] = 128 VGPR (~210 tot).
// Stage = 6 loads/thread (A:2, B:4) -> steady vmcnt(6), tail vmcnt(0).
__global__ void gemm_qkv3(const u16* __restrict__ A, const u16* __restrict__ Bt,
                          u16* __restrict__ Qo, u16* __restrict__ Ko, u16* __restrict__ Vo) {
  __shared__ u16 lA[3][128 * 32];   // 8KB per buffer
  __shared__ u16 lB[3][256 * 32];   // 16KB per buffer
  const int tid = threadIdx.x;
  const int lane = tid & 63;
  const int w = tid >> 6;            // wave 0..3 -> B-cols w*64..w*64+63
  const int bm = blockIdx.x * 128;
  const int bn = blockIdx.y * 256;   // 0..5888
  const int fr = lane & 15, fq = lane >> 4;
  const int K = D_;
  const int KT = K >> 5;             // 64
  f32x4 acc[8][4] = {};

  auto stage = [&](int buf, int kt) {
    const int k0 = kt << 5;
    #pragma unroll
    for (int c = w; c < 8; c += 4) {      // A: 8 chunks of 16 rows
      const int r = c * 16 + (lane >> 2);
      const int col = ((lane & 3) ^ ((r >> 1) & 3)) * 8;
      async_copy16(A + (size_t)(bm + r) * K + k0 + col, &lA[buf][c * 512]);
    }
    #pragma unroll
    for (int c = w; c < 16; c += 4) {     // B: 16 chunks of 16 rows
      const int r = c * 16 + (lane >> 2);
      const int col = ((lane & 3) ^ ((r >> 1) & 3)) * 8;
      async_copy16(Bt + (size_t)(bn + r) * K + k0 + col, &lB[buf][c * 512]);
    }
  };

  stage(0, 0);
  stage(1, 1);
  asm volatile("s_waitcnt vmcnt(6)" ::: "memory");   // tile 0's 6 landed; tile 1 in flight
  __builtin_amdgcn_s_barrier();
  asm volatile("" ::: "memory");

  int p = 0, sb = 2;
  #pragma unroll 1
  for (int kt = 0; kt < KT; ++kt) {
    if (kt + 2 < KT) stage(sb, kt + 2);
    bf16x8 af[8], bfr[4];
    #pragma unroll
    for (int i = 0; i < 8; ++i) {
      const int ra = i * 16 + fr;
      af[i] = *(const bf16x8*)&lA[p][ra * 32 + ((fq ^ ((ra >> 1) & 3)) * 8)];
    }
    #pragma unroll
    for (int j = 0; j < 4; ++j) {
      const int rb = w * 64 + j * 16 + fr;
      bfr[j] = *(const bf16x8*)&lB[p][rb * 32 + ((fq ^ ((rb >> 1) & 3)) * 8)];
    }
    #pragma unroll
    for (int i = 0; i < 8; ++i)
      #pragma unroll
      for (int j = 0; j < 4; ++j)
        acc[i][j] = __builtin_amdgcn_mfma_f32_16x16x32_bf16(af[i], bfr[j], acc[i][j], 0, 0, 0);
    if (kt + 1 < KT) {
      if (kt + 2 < KT) asm volatile("s_waitcnt vmcnt(6)" ::: "memory");  // kt+1 landed
      else             asm volatile("s_waitcnt vmcnt(0)" ::: "memory");  // tail drain
      __builtin_amdgcn_s_barrier();
      asm volatile("" ::: "memory");
    }
    p  = (p == 2) ? 0 : p + 1;
    sb = (sb == 2) ? 0 : sb + 1;
  }
  // route by bn (tile never straddles the 2048/4096 boundaries: 256 | 2048)
  u16* out = (bn < 2048) ? Qo : (bn < 4096) ? Ko : Vo;
  const int bnl = bn & 2047;
  #pragma unroll
  for (int i = 0; i < 8; ++i)
    #pragma unroll
    for (int j = 0; j < 4; ++j) {
      const int row = bm + i * 16 + fq * 4;
      const int col = bnl + w * 64 + j * 16 + fr;
      #pragma unroll
      for (int r = 0; r < 4; ++r)
        out[(size_t)(row + r) * D_ + col] = f2bf(acc[i][j][r]);
    }
}

// ---------------- causal flash attention, KV-split + swapped-QK softmax + Q-RoPE ----------------
// Round-15: + defer-max (T13, THR=12): skip the O-rescale when no lane's row-max
// grew by >12 log2 units. NaN-safe: first processed tile of each (q-tile,split)
// is fully unmasked -> mrow finite before any fully-masked row appears.
#define QB 64
#define KB 32
#define PLD 36    // P row stride (72B): [q][kv] layout; b64 reads aligned

__global__ __launch_bounds__(256, 2)
void attn_fwd(const u16* __restrict__ Qg, const u16* __restrict__ Kg,
              const u16* __restrict__ Vg, const float2* __restrict__ tab,
              u16* __restrict__ po0, u16* __restrict__ po1, float2* __restrict__ ml) {
  __shared__ u16 lK[2][KB * HD_];   // linear [kv][hd], source-swizzled content
  __shared__ u16 lV[2][HD_ * 40];   // swizzled V^T
  __shared__ u16 lP[4][16 * PLD];   // per-wave P 16x32, [q][kv]
  const int tid = threadIdx.x;
  const int lane = tid & 63;
  const int w = tid >> 6;
  const int fr = lane & 15, fq = lane >> 4;
  const int xA = blockIdx.x;                 // 0..15
  const int bh = blockIdx.y;
  const int split = blockIdx.z;
  const size_t base = (size_t)(bh >> 4) * S_ * D_ + (size_t)(bh & 15) * HD_;
  const int qA = xA * QB, qB = (31 - xA) * QB;
  const int ntA = (qA + QB) / KB;            // 2..32
  const int ntB = (qB + QB) / KB;            // 34..64
  const int c = (ntA <= 16) ? (33 - ntA) : 16;   // balanced split point
  const int t0 = split ? c : 0;
  const int t1 = split ? ntB : c;
  const float kscale = 0.08838834764831843f * 1.4426950408889634f; // 1/sqrt(128)*log2e

  // Q fragments for both q-tiles (row=lane&15 -> q, k=(lane>>4)*8+j -> hd)
  bf16x8 qfA[4], qfB[4];
  {
    const u16* qpa = Qg + base + (size_t)(qA + w * 16 + fr) * D_ + fq * 8;
    const u16* qpb = Qg + base + (size_t)(qB + w * 16 + fr) * D_ + fq * 8;
    #pragma unroll
    for (int kk = 0; kk < 4; ++kk) {
      qfA[kk] = *(const bf16x8*)(qpa + kk * 32);
      qfB[kk] = *(const bf16x8*)(qpb + kk * 32);
    }
    // in-register Q-RoPE: d2 = kk*32 + fq*8 + j pairs with d2+64 (kk+2)
    const float2* tA = &tab[(qA + w * 16 + fr) * 64 + fq * 8];
    const float2* tB = &tab[(qB + w * 16 + fr) * 64 + fq * 8];
    #pragma unroll
    for (int kk = 0; kk < 2; ++kk)
      #pragma unroll
      for (int j = 0; j < 8; ++j) {
        const float2 ca = tA[kk * 32 + j];
        float t1 = bf2f((u16)qfA[kk][j]), t2 = bf2f((u16)qfA[kk + 2][j]);
        qfA[kk][j]     = (short)f2bf(t1 * ca.x - t2 * ca.y);
        qfA[kk + 2][j] = (short)f2bf(t1 * ca.y + t2 * ca.x);
        const float2 cb = tB[kk * 32 + j];
        t1 = bf2f((u16)qfB[kk][j]); t2 = bf2f((u16)qfB[kk + 2][j]);
        qfB[kk][j]     = (short)f2bf(t1 * cb.x - t2 * cb.y);
        qfB[kk + 2][j] = (short)f2bf(t1 * cb.y + t2 * cb.x);
      }
  }
  f32x4 oA[8] = {}, oB[8] = {};
  float mAs = -INFINITY, lAs = 0.f, mBs = -INFINITY, lBs = 0.f;

  auto stageK = [&](int buf, int kv0) {
    #pragma unroll
    for (int cc = w; cc < 8; cc += 4) {
      const int row = cc * 4 + (lane >> 4);
      const int slot = (lane & 15) ^ (row & 7);
      async_copy16(Kg + base + (size_t)(kv0 + row) * D_ + slot * 8, &lK[buf][cc * 512]);
    }
  };
  const int srow = tid >> 3, sc0 = (tid & 7) * 16;
  const u32 swz = (u32)((sc0 >> 4) & 7) << 4;
  const u32 rb = (u32)srow * 2;
  u16x8_t rv0, rv1;
  auto loadV = [&](int kv0) {
    const u16* gv = Vg + base + (size_t)(kv0 + srow) * D_ + sc0;
    rv0 = *(const u16x8_t*)gv; rv1 = *(const u16x8_t*)(gv + 8);
  };
  auto writeV = [&](int buf) {
    char* lv = (char*)&lV[buf][0];
    #pragma unroll
    for (int j = 0; j < 8; ++j) {
      *(u16*)(lv + ((((u32)(sc0 + j) * 80) + rb) ^ swz))     = rv0[j];
      *(u16*)(lv + ((((u32)(sc0 + 8 + j) * 80) + rb) ^ swz)) = rv1[j];
    }
  };

  // swapped-layout softmax + defer-max: lane owns q=fr's row, kv slots fq*4+r (+16c)
  auto softmax_sw = [&](const f32x4& s0, const f32x4& s1, float& mrow, float& lrow,
                        f32x4* o, int q0t, int kv0) {
    const int qg = q0t + w * 16 + fr;
    const bool notfull = (kv0 + KB - 1 > q0t);
    float v[8];
    #pragma unroll
    for (int r = 0; r < 4; ++r) {
      v[r]     = s0[r] * kscale;
      v[4 + r] = s1[r] * kscale;
      if (notfull) {
        if (kv0 + fq * 4 + r > qg)      v[r]     = -INFINITY;
        if (kv0 + 16 + fq * 4 + r > qg) v[4 + r] = -INFINITY;
      }
    }
    float mx = fmaxf(fmaxf(fmaxf(v[0], v[1]), fmaxf(v[2], v[3])),
                     fmaxf(fmaxf(v[4], v[5]), fmaxf(v[6], v[7])));
    mx = fmaxf(mx, __shfl_xor(mx, 16));
    mx = fmaxf(mx, __shfl_xor(mx, 32));
    // T13 defer-max: rescale only when some row's max grew by > 12 log2 units
    const int nogrow = (mx <= mrow + 12.f);
    if (!__all(nogrow)) {
      const float mn = fmaxf(mrow, mx);
      const float al = exp2f(mrow - mn);
      mrow = mn;
      lrow *= al;
      #pragma unroll
      for (int r = 0; r < 4; ++r) {
        const float ab = __shfl(al, fq * 4 + r);
        #pragma unroll
        for (int nb = 0; nb < 8; ++nb) o[nb][r] *= ab;
      }
    }
    float p[8];
    #pragma unroll
    for (int j = 0; j < 8; ++j) p[j] = exp2f(v[j] - mrow);
    float rs = ((p[0] + p[1]) + (p[2] + p[3])) + ((p[4] + p[5]) + (p[6] + p[7]));
    rs += __shfl_xor(rs, 16);
    rs += __shfl_xor(rs, 32);
    lrow += rs;
    #pragma unroll
    for (int r = 0; r < 4; ++r) {
      lP[w][fr * PLD + fq * 4 + r]      = f2bf(p[r]);
      lP[w][fr * PLD + 16 + fq * 4 + r] = f2bf(p[4 + r]);
    }
  };

  auto pv = [&](f32x4* o, const bf16x8* vf) {
    u32x2 pa0 = *(const u32x2*)&lP[w][fr * PLD + fq * 8];
    u32x2 pa1 = *(const u32x2*)&lP[w][fr * PLD + fq * 8 + 4];
    u32x4 pc; pc[0] = pa0[0]; pc[1] = pa0[1]; pc[2] = pa1[0]; pc[3] = pa1[1];
    const bf16x8 pa = __builtin_bit_cast(bf16x8, pc);
    #pragma unroll
    for (int nb = 0; nb < 8; ++nb)
      o[nb] = __builtin_amdgcn_mfma_f32_16x16x32_bf16(pa, vf[nb], o[nb], 0, 0, 0);
  };

  // prologue: stage tile t0 into buffer 0
  stageK(0, t0 * KB);
  loadV(t0 * KB);
  writeV(0);

  for (int t = t0; t < t1; ++t) {
    const int kv0 = t * KB;
    const int cur = (t - t0) & 1, nxt = cur ^ 1;
    __syncthreads();   // drains vmcnt/lgkmcnt: lK[cur] DMA + lV[cur] writes visible
    if (t + 1 < t1) {
      stageK(nxt, kv0 + KB);   // async DMA, drained by next barrier
      loadV(kv0 + KB);         // regs; consumed by writeV after compute
    }

    const bool doA = (t < ntA);
    // SWAPPED QK^T: mfma(K, Q) -> lane owns one q-row's scores
    f32x4 sA0 = {}, sA1 = {}, sB0 = {}, sB1 = {};
    #pragma unroll
    for (int kk = 0; kk < 4; ++kk) {
      const int sl = ((kk * 4 + fq) ^ (fr & 7)) * 16;
      bf16x8 k0f = *(const bf16x8*)((const char*)&lK[cur][0] + fr * 256 + sl);
      bf16x8 k1f = *(const bf16x8*)((const char*)&lK[cur][0] + (16 + fr) * 256 + sl);
      if (doA) {
        sA0 = __builtin_amdgcn_mfma_f32_16x16x32_bf16(k0f, qfA[kk], sA0, 0, 0, 0);
        sA1 = __builtin_amdgcn_mfma_f32_16x16x32_bf16(k1f, qfA[kk], sA1, 0, 0, 0);
      }
      sB0 = __builtin_amdgcn_mfma_f32_16x16x32_bf16(k0f, qfB[kk], sB0, 0, 0, 0);
      sB1 = __builtin_amdgcn_mfma_f32_16x16x32_bf16(k1f, qfB[kk], sB1, 0, 0, 0);
    }

    bf16x8 vf[8];
    #pragma unroll
    for (int nb = 0; nb < 8; ++nb) {
      const u32 off = (((u32)(nb * 16 + fr) * 80) + (u32)fq * 16) ^ ((u32)nb << 4);
      vf[nb] = *(const bf16x8*)((const char*)&lV[cur][0] + off);
    }

    if (doA) { softmax_sw(sA0, sA1, mAs, lAs, oA, qA, kv0); pv(oA, vf); }
    softmax_sw(sB0, sB1, mBs, lBs, oB, qB, kv0);
    pv(oB, vf);

    if (t + 1 < t1) writeV(nxt);   // after compute
  }

  // epilogue: write UNNORMALIZED partials + (m,l) per row
  u16* po = split ? po1 : po0;
  float2* mlp = ml + (size_t)split * (B_ * H_ * S_) + (size_t)bh * S_;
  if (lane < 16) {
    mlp[qA + w * 16 + fr] = make_float2(mAs, lAs);
    mlp[qB + w * 16 + fr] = make_float2(mBs, lBs);
  }
  #pragma unroll
  for (int r = 0; r < 4; ++r) {
    const int rowA = qA + w * 16 + fq * 4 + r;
    const int rowB = qB + w * 16 + fq * 4 + r;
    u16* orA = po + base + (size_t)rowA * D_;
    u16* orB = po + base + (size_t)rowB * D_;
    #pragma unroll
    for (int nb = 0; nb < 8; ++nb) {
      orA[nb * 16 + fr] = f2bf(oA[nb][r]);
      orB[nb * 16 + fr] = f2bf(oB[nb][r]);
    }
  }
}

// ---------------- combine the 2 KV-splits ----------------
__global__ void attn_combine(const u16* __restrict__ po0, const u16* __restrict__ po1,
                             const float2* __restrict__ ml, u16* __restrict__ Og) {
  const int idx = blockIdx.x * blockDim.x + threadIdx.x;  // B*H*S*16
  const int d8 = (idx & 15) * 8;
  const int row = idx >> 4;            // bh*S + s
  const int bh = row >> 11, s = row & (S_ - 1);
  const float2 v0 = ml[row];
  const float2 v1 = ml[B_ * H_ * S_ + row];
  const float m = fmaxf(v0.x, v1.x);
  const float e0 = exp2f(v0.x - m), e1 = exp2f(v1.x - m);
  const float inv = 1.0f / (v0.y * e0 + v1.y * e1);
  const size_t off = (size_t)(bh >> 4) * S_ * D_ + (size_t)s * D_ + (bh & 15) * HD_ + d8;
  u16x8_t a = *(const u16x8_t*)(po0 + off);
  u16x8_t b = *(const u16x8_t*)(po1 + off);
  u16x8_t o;
  #pragma unroll
  for (int j = 0; j < 8; ++j)
    o[j] = f2bf((bf2f(a[j]) * e0 + bf2f(b[j]) * e1) * inv);
  *(u16x8_t*)(Og + off) = o;
}

// ---------------- launch ----------------
extern "C" void kernel_launch(void* const* d_in, const int* in_sizes, int n_in,
                              void* d_out, int out_size, void* d_ws, size_t ws_size,
                              hipStream_t stream) {
  const float* x  = (const float*)d_in[0];
  const float* Wq = (const float*)d_in[1];
  const float* Wk = (const float*)d_in[2];
  const float* Wv = (const float*)d_in[3];
  const float* Wo = (const float*)d_in[4];
  const int* pos  = (const int*)d_in[5];

  char* p = (char*)d_ws;
  u16* xb  = (u16*)p; p += (size_t)B_ * S_ * D_ * 2;
  u16* Wqb = (u16*)p; p += (size_t)D_ * D_ * 2;   // Wq/Wk/Wv contiguous -> packed [6144][2048]
  u16* Wkb = (u16*)p; p += (size_t)D_ * D_ * 2;
  u16* Wvb = (u16*)p; p += (size_t)D_ * D_ * 2;
  u16* Wob = (u16*)p; p += (size_t)D_ * D_ * 2;
  u16* Qb  = (u16*)p; p += (size_t)B_ * S_ * D_ * 2;
  u16* Kb  = (u16*)p; p += (size_t)B_ * S_ * D_ * 2;
  u16* Vb  = (u16*)p; p += (size_t)B_ * S_ * D_ * 2;
  float2* tab = (float2*)p; p += (size_t)S_ * 64 * sizeof(float2);
  float2* ml  = (float2*)p; p += (size_t)2 * B_ * H_ * S_ * sizeof(float2);
  // partial-O buffers reuse dead regions (xb, Wqb+Wkb dead after gemm_qkv3)
  u16* po0 = xb;
  u16* po1 = Wqb;
  u16* Ob  = Qb;  // combined attention output overwrites Q (attn reads Q first)

  cvt_all<<<24576, 256, 0, stream>>>(x, Wq, Wk, Wv, Wo, xb);
  rope_table<<<(S_ * 64) / 256, 256, 0, stream>>>(pos, tab);

  // fused QKV projection: 128x256 tiles, grid (32,24)=768 blocks = 3/CU uniform
  gemm_qkv3<<<dim3(B_ * S_ / 128, 24), 256, 0, stream>>>(xb, Wqb, Qb, Kb, Vb);

  // standalone K-RoPE (Q roped in-register inside attn)
  rope_k<<<(B_ * S_ * H_ * 16) / 256, 256, 0, stream>>>(Kb, tab);

  // KV-split flash attention + combine
  attn_fwd<<<dim3(16, B_ * H_, 2), 256, 0, stream>>>(Qb, Kb, Vb, tab, po0, po1, ml);
  attn_combine<<<(B_ * H_ * S_ * 16) / 256, 256, 0, stream>>>(po0, po1, ml, Ob);

  gemm_bt<true><<<dim3(B_ * S_ / 128, D_ / 128), 256, 0, stream>>>(Ob, Wob, (float*)d_out, B_ * S_, D_, D_);
}

// Round 16
// 334.067 us; speedup vs baseline: 2.7216x; 2.7216x over previous
//
#include <hip/hip_runtime.h>
#include <math.h>

// Problem constants
#define B_  2
#define S_  2048
#define D_  2048
#define H_  16
#define HD_ 128

using u16 = unsigned short;
using u32 = unsigned int;
typedef __attribute__((ext_vector_type(4))) float f32x4;
typedef __attribute__((ext_vector_type(8))) short bf16x8;   // 8 bf16 = 4 VGPRs (MFMA A/B frag)
using u16x4_t = __attribute__((ext_vector_type(4))) unsigned short;
using u16x8_t = __attribute__((ext_vector_type(8))) unsigned short;
typedef __attribute__((ext_vector_type(2))) u32 u32x2;
typedef __attribute__((ext_vector_type(4))) u32 u32x4;

__device__ __forceinline__ u16 f2bf(float f) {
  u32 u = __builtin_bit_cast(u32, f);
  u32 r = u + 0x7fffu + ((u >> 16) & 1u);   // RNE
  return (u16)(r >> 16);
}
__device__ __forceinline__ float bf2f(u16 x) {
  u32 u = ((u32)x) << 16;
  return __builtin_bit_cast(float, u);
}
// async global->LDS, 16B per lane; LDS dest = wave-uniform base + lane*16;
// global source address is PER-LANE (enables source-side swizzling).
__device__ __forceinline__ void async_copy16(const u16* g, u16* l) {
  __builtin_amdgcn_global_load_lds((const __attribute__((address_space(1))) u32*)g,
                                   (__attribute__((address_space(3))) u32*)l, 16, 0, 0);
}

// ---------------- fused fp32 -> bf16 convert (x, Wq, Wk, Wv, Wo in one pass) ----------------
__global__ void cvt_all(const float* __restrict__ x, const float* __restrict__ Wq,
                        const float* __restrict__ Wk, const float* __restrict__ Wv,
                        const float* __restrict__ Wo, u16* __restrict__ dst) {
  const int i = (blockIdx.x * blockDim.x + threadIdx.x) * 4;
  if (i >= 25165824) return;
  const float* src;
  int off;
  if (i < (1 << 23)) { src = x; off = i; }
  else {
    const int wi = i - (1 << 23);
    const int which = wi >> 22;
    off = wi & ((1 << 22) - 1);
    src = (which == 0) ? Wq : (which == 1) ? Wk : (which == 2) ? Wv : Wo;
  }
  float4 v = *(const float4*)(src + off);
  u16x4_t o;
  o[0] = f2bf(v.x); o[1] = f2bf(v.y); o[2] = f2bf(v.z); o[3] = f2bf(v.w);
  *(u16x4_t*)(dst + i) = o;
}

// ---------------- RoPE cos/sin table ----------------
__global__ void rope_table(const int* __restrict__ pos, float2* __restrict__ tab) {
  int t = blockIdx.x * blockDim.x + threadIdx.x;  // S*64
  if (t >= S_ * 64) return;
  int s = t >> 6, i = t & 63;
  float freq = expf(-(float)i * (9.210340371976184f / 64.0f));  // theta^{-i/64}
  float ang = (float)pos[s] * freq;
  tab[t] = make_float2(cosf(ang), sinf(ang));
}

// ---------------- K-only RoPE (proven standalone) ----------------
__global__ void rope_k(u16* __restrict__ K, const float2* __restrict__ tab) {
  int t = blockIdx.x * blockDim.x + threadIdx.x;  // B*S*H*16
  int g = t & 15;
  int bsh = t >> 4;
  int h = bsh & (H_ - 1);
  int bs = bsh >> 4;            // b*S + s
  int s = bs & (S_ - 1);
  size_t base = (size_t)bs * D_ + (size_t)h * HD_;
  int d2 = g * 4;
  const float2* tb = &tab[s * 64 + d2];
  float2 cs[4];
  #pragma unroll
  for (int j = 0; j < 4; ++j) cs[j] = tb[j];
  u16x4_t a = *(u16x4_t*)(K + base + d2);
  u16x4_t c = *(u16x4_t*)(K + base + 64 + d2);
  u16x4_t ra, rc;
  #pragma unroll
  for (int j = 0; j < 4; ++j) {
    float t1 = bf2f(a[j]), t2 = bf2f(c[j]);
    ra[j] = f2bf(t1 * cs[j].x - t2 * cs[j].y);
    rc[j] = f2bf(t1 * cs[j].y + t2 * cs[j].x);
  }
  *(u16x4_t*)(K + base + d2) = ra;
  *(u16x4_t*)(K + base + 64 + d2) = rc;
}

// ---------------- GEMM: C = A(MxK) * Bt(NxK)^T (128x128, round-10 proven) ----------------
template <bool F32OUT>
__global__ __launch_bounds__(256, 2)
void gemm_bt(const u16* __restrict__ A, const u16* __restrict__ Bt,
             void* __restrict__ Cout, int M, int N, int K) {
  __shared__ u16 lA[3][128 * 32];
  __shared__ u16 lB[3][128 * 32];
  const int tid = threadIdx.x;
  const int lane = tid & 63;
  const int w = tid >> 6;            // wave 0..3
  const int wr = w >> 1, wc = w & 1; // 2x2 waves of 64x64
  const int bm = blockIdx.x * 128;
  const int bn = blockIdx.y * 128;
  const int fr = lane & 15, fq = lane >> 4;
  const int KT = K >> 5;
  f32x4 acc[4][4] = {};

  auto stage = [&](int buf, int kt) {
    const int k0 = kt << 5;
    #pragma unroll
    for (int c = w; c < 8; c += 4) {
      const int r = c * 16 + (lane >> 2);
      const int col = ((lane & 3) ^ ((r >> 1) & 3)) * 8;   // pre-swizzled source slot
      async_copy16(A + (size_t)(bm + r) * K + k0 + col, &lA[buf][c * 512]);
      async_copy16(Bt + (size_t)(bn + r) * K + k0 + col, &lB[buf][c * 512]);
    }
  };

  stage(0, 0);
  stage(1, 1);
  asm volatile("s_waitcnt vmcnt(4)" ::: "memory");   // tile 0 landed; tile 1 in flight
  __builtin_amdgcn_s_barrier();
  asm volatile("" ::: "memory");

  int p = 0, sb = 2;
  #pragma unroll 1
  for (int kt = 0; kt < KT; ++kt) {
    if (kt + 2 < KT) stage(sb, kt + 2);
    bf16x8 af[4], bfr[4];
    #pragma unroll
    for (int i = 0; i < 4; ++i) {
      const int ra = wr * 64 + i * 16 + fr;
      const int rb = wc * 64 + i * 16 + fr;
      af[i]  = *(const bf16x8*)&lA[p][ra * 32 + ((fq ^ ((ra >> 1) & 3)) * 8)];
      bfr[i] = *(const bf16x8*)&lB[p][rb * 32 + ((fq ^ ((rb >> 1) & 3)) * 8)];
    }
    #pragma unroll
    for (int i = 0; i < 4; ++i)
      #pragma unroll
      for (int j = 0; j < 4; ++j)
        acc[i][j] = __builtin_amdgcn_mfma_f32_16x16x32_bf16(af[i], bfr[j], acc[i][j], 0, 0, 0);
    if (kt + 1 < KT) {
      if (kt + 2 < KT) asm volatile("s_waitcnt vmcnt(4)" ::: "memory");  // kt+1 landed
      else             asm volatile("s_waitcnt vmcnt(0)" ::: "memory");  // tail drain
      __builtin_amdgcn_s_barrier();
      asm volatile("" ::: "memory");
    }
    p  = (p == 2) ? 0 : p + 1;
    sb = (sb == 2) ? 0 : sb + 1;
  }
  // C/D layout: col = lane&15, row = (lane>>4)*4 + reg  [m89/m91 verified]
  #pragma unroll
  for (int i = 0; i < 4; ++i)
    #pragma unroll
    for (int j = 0; j < 4; ++j) {
      const int row = bm + wr * 64 + i * 16 + fq * 4;
      const int col = bn + wc * 64 + j * 16 + fr;
      #pragma unroll
      for (int r = 0; r < 4; ++r) {
        const float v = acc[i][j][r];
        if (F32OUT) ((float*)Cout)[(size_t)(row + r) * N + col] = v;
        else        ((u16*)Cout)[(size_t)(row + r) * N + col] = f2bf(v);
      }
    }
}

// ---------------- fused QKV GEMM, 128x256 tile / 4 waves / 128x64 per wave ----------------
// Round-15 structure + round-16 fix: __launch_bounds__(256,2) -> 256-VGPR cap.
// Without it hipcc targeted 64 VGPR and spilled the 128-reg accumulator to
// scratch (1.18 GB writes, 730 us). LDS 72KB already limits to 2 blocks/CU
// (= 2 waves/SIMD), so the bound costs no occupancy.
// Per K-step per wave: 32 MFMA / 12 ds_read (vs 16/8 at 128x128).
// Grid (32,24)=768 = 3 blocks/CU-pair uniform; stage = 6 loads/thread ->
// steady vmcnt(6), tail vmcnt(0).
__global__ __launch_bounds__(256, 2)
void gemm_qkv3(const u16* __restrict__ A, const u16* __restrict__ Bt,
               u16* __restrict__ Qo, u16* __restrict__ Ko, u16* __restrict__ Vo) {
  __shared__ u16 lA[3][128 * 32];   // 8KB per buffer
  __shared__ u16 lB[3][256 * 32];   // 16KB per buffer
  const int tid = threadIdx.x;
  const int lane = tid & 63;
  const int w = tid >> 6;            // wave 0..3 -> B-cols w*64..w*64+63
  const int bm = blockIdx.x * 128;
  const int bn = blockIdx.y * 256;   // 0..5888
  const int fr = lane & 15, fq = lane >> 4;
  const int K = D_;
  const int KT = K >> 5;             // 64
  f32x4 acc[8][4] = {};

  auto stage = [&](int buf, int kt) {
    const int k0 = kt << 5;
    #pragma unroll
    for (int c = w; c < 8; c += 4) {      // A: 8 chunks of 16 rows
      const int r = c * 16 + (lane >> 2);
      const int col = ((lane & 3) ^ ((r >> 1) & 3)) * 8;
      async_copy16(A + (size_t)(bm + r) * K + k0 + col, &lA[buf][c * 512]);
    }
    #pragma unroll
    for (int c = w; c < 16; c += 4) {     // B: 16 chunks of 16 rows
      const int r = c * 16 + (lane >> 2);
      const int col = ((lane & 3) ^ ((r >> 1) & 3)) * 8;
      async_copy16(Bt + (size_t)(bn + r) * K + k0 + col, &lB[buf][c * 512]);
    }
  };

  stage(0, 0);
  stage(1, 1);
  asm volatile("s_waitcnt vmcnt(6)" ::: "memory");   // tile 0's 6 landed; tile 1 in flight
  __builtin_amdgcn_s_barrier();
  asm volatile("" ::: "memory");

  int p = 0, sb = 2;
  #pragma unroll 1
  for (int kt = 0; kt < KT; ++kt) {
    if (kt + 2 < KT) stage(sb, kt + 2);
    bf16x8 af[8], bfr[4];
    #pragma unroll
    for (int i = 0; i < 8; ++i) {
      const int ra = i * 16 + fr;
      af[i] = *(const bf16x8*)&lA[p][ra * 32 + ((fq ^ ((ra >> 1) & 3)) * 8)];
    }
    #pragma unroll
    for (int j = 0; j < 4; ++j) {
      const int rb = w * 64 + j * 16 + fr;
      bfr[j] = *(const bf16x8*)&lB[p][rb * 32 + ((fq ^ ((rb >> 1) & 3)) * 8)];
    }
    #pragma unroll
    for (int i = 0; i < 8; ++i)
      #pragma unroll
      for (int j = 0; j < 4; ++j)
        acc[i][j] = __builtin_amdgcn_mfma_f32_16x16x32_bf16(af[i], bfr[j], acc[i][j], 0, 0, 0);
    if (kt + 1 < KT) {
      if (kt + 2 < KT) asm volatile("s_waitcnt vmcnt(6)" ::: "memory");  // kt+1 landed
      else             asm volatile("s_waitcnt vmcnt(0)" ::: "memory");  // tail drain
      __builtin_amdgcn_s_barrier();
      asm volatile("" ::: "memory");
    }
    p  = (p == 2) ? 0 : p + 1;
    sb = (sb == 2) ? 0 : sb + 1;
  }
  // route by bn (tile never straddles the 2048/4096 boundaries: 256 | 2048)
  u16* out = (bn < 2048) ? Qo : (bn < 4096) ? Ko : Vo;
  const int bnl = bn & 2047;
  #pragma unroll
  for (int i = 0; i < 8; ++i)
    #pragma unroll
    for (int j = 0; j < 4; ++j) {
      const int row = bm + i * 16 + fq * 4;
      const int col = bnl + w * 64 + j * 16 + fr;
      #pragma unroll
      for (int r = 0; r < 4; ++r)
        out[(size_t)(row + r) * D_ + col] = f2bf(acc[i][j][r]);
    }
}

// ---------------- causal flash attention, KV-split + swapped-QK softmax + Q-RoPE ----------------
// + defer-max (T13, THR=12). NaN-safe: first processed tile of each
// (q-tile,split) is fully unmasked -> mrow finite before any fully-masked row.
#define QB 64
#define KB 32
#define PLD 36    // P row stride (72B): [q][kv] layout; b64 reads aligned

__global__ __launch_bounds__(256, 2)
void attn_fwd(const u16* __restrict__ Qg, const u16* __restrict__ Kg,
              const u16* __restrict__ Vg, const float2* __restrict__ tab,
              u16* __restrict__ po0, u16* __restrict__ po1, float2* __restrict__ ml) {
  __shared__ u16 lK[2][KB * HD_];   // linear [kv][hd], source-swizzled content
  __shared__ u16 lV[2][HD_ * 40];   // swizzled V^T
  __shared__ u16 lP[4][16 * PLD];   // per-wave P 16x32, [q][kv]
  const int tid = threadIdx.x;
  const int lane = tid & 63;
  const int w = tid >> 6;
  const int fr = lane & 15, fq = lane >> 4;
  const int xA = blockIdx.x;                 // 0..15
  const int bh = blockIdx.y;
  const int split = blockIdx.z;
  const size_t base = (size_t)(bh >> 4) * S_ * D_ + (size_t)(bh & 15) * HD_;
  const int qA = xA * QB, qB = (31 - xA) * QB;
  const int ntA = (qA + QB) / KB;            // 2..32
  const int ntB = (qB + QB) / KB;            // 34..64
  const int c = (ntA <= 16) ? (33 - ntA) : 16;   // balanced split point
  const int t0 = split ? c : 0;
  const int t1 = split ? ntB : c;
  const float kscale = 0.08838834764831843f * 1.4426950408889634f; // 1/sqrt(128)*log2e

  // Q fragments for both q-tiles (row=lane&15 -> q, k=(lane>>4)*8+j -> hd)
  bf16x8 qfA[4], qfB[4];
  {
    const u16* qpa = Qg + base + (size_t)(qA + w * 16 + fr) * D_ + fq * 8;
    const u16* qpb = Qg + base + (size_t)(qB + w * 16 + fr) * D_ + fq * 8;
    #pragma unroll
    for (int kk = 0; kk < 4; ++kk) {
      qfA[kk] = *(const bf16x8*)(qpa + kk * 32);
      qfB[kk] = *(const bf16x8*)(qpb + kk * 32);
    }
    // in-register Q-RoPE: d2 = kk*32 + fq*8 + j pairs with d2+64 (kk+2)
    const float2* tA = &tab[(qA + w * 16 + fr) * 64 + fq * 8];
    const float2* tB = &tab[(qB + w * 16 + fr) * 64 + fq * 8];
    #pragma unroll
    for (int kk = 0; kk < 2; ++kk)
      #pragma unroll
      for (int j = 0; j < 8; ++j) {
        const float2 ca = tA[kk * 32 + j];
        float t1 = bf2f((u16)qfA[kk][j]), t2 = bf2f((u16)qfA[kk + 2][j]);
        qfA[kk][j]     = (short)f2bf(t1 * ca.x - t2 * ca.y);
        qfA[kk + 2][j] = (short)f2bf(t1 * ca.y + t2 * ca.x);
        const float2 cb = tB[kk * 32 + j];
        t1 = bf2f((u16)qfB[kk][j]); t2 = bf2f((u16)qfB[kk + 2][j]);
        qfB[kk][j]     = (short)f2bf(t1 * cb.x - t2 * cb.y);
        qfB[kk + 2][j] = (short)f2bf(t1 * cb.y + t2 * cb.x);
      }
  }
  f32x4 oA[8] = {}, oB[8] = {};
  float mAs = -INFINITY, lAs = 0.f, mBs = -INFINITY, lBs = 0.f;

  auto stageK = [&](int buf, int kv0) {
    #pragma unroll
    for (int cc = w; cc < 8; cc += 4) {
      const int row = cc * 4 + (lane >> 4);
      const int slot = (lane & 15) ^ (row & 7);
      async_copy16(Kg + base + (size_t)(kv0 + row) * D_ + slot * 8, &lK[buf][cc * 512]);
    }
  };
  const int srow = tid >> 3, sc0 = (tid & 7) * 16;
  const u32 swz = (u32)((sc0 >> 4) & 7) << 4;
  const u32 rb = (u32)srow * 2;
  u16x8_t rv0, rv1;
  auto loadV = [&](int kv0) {
    const u16* gv = Vg + base + (size_t)(kv0 + srow) * D_ + sc0;
    rv0 = *(const u16x8_t*)gv; rv1 = *(const u16x8_t*)(gv + 8);
  };
  auto writeV = [&](int buf) {
    char* lv = (char*)&lV[buf][0];
    #pragma unroll
    for (int j = 0; j < 8; ++j) {
      *(u16*)(lv + ((((u32)(sc0 + j) * 80) + rb) ^ swz))     = rv0[j];
      *(u16*)(lv + ((((u32)(sc0 + 8 + j) * 80) + rb) ^ swz)) = rv1[j];
    }
  };

  // swapped-layout softmax + defer-max: lane owns q=fr's row, kv slots fq*4+r (+16c)
  auto softmax_sw = [&](const f32x4& s0, const f32x4& s1, float& mrow, float& lrow,
                        f32x4* o, int q0t, int kv0) {
    const int qg = q0t + w * 16 + fr;
    const bool notfull = (kv0 + KB - 1 > q0t);
    float v[8];
    #pragma unroll
    for (int r = 0; r < 4; ++r) {
      v[r]     = s0[r] * kscale;
      v[4 + r] = s1[r] * kscale;
      if (notfull) {
        if (kv0 + fq * 4 + r > qg)      v[r]     = -INFINITY;
        if (kv0 + 16 + fq * 4 + r > qg) v[4 + r] = -INFINITY;
      }
    }
    float mx = fmaxf(fmaxf(fmaxf(v[0], v[1]), fmaxf(v[2], v[3])),
                     fmaxf(fmaxf(v[4], v[5]), fmaxf(v[6], v[7])));
    mx = fmaxf(mx, __shfl_xor(mx, 16));
    mx = fmaxf(mx, __shfl_xor(mx, 32));
    // T13 defer-max: rescale only when some row's max grew by > 12 log2 units
    const int nogrow = (mx <= mrow + 12.f);
    if (!__all(nogrow)) {
      const float mn = fmaxf(mrow, mx);
      const float al = exp2f(mrow - mn);
      mrow = mn;
      lrow *= al;
      #pragma unroll
      for (int r = 0; r < 4; ++r) {
        const float ab = __shfl(al, fq * 4 + r);
        #pragma unroll
        for (int nb = 0; nb < 8; ++nb) o[nb][r] *= ab;
      }
    }
    float p[8];
    #pragma unroll
    for (int j = 0; j < 8; ++j) p[j] = exp2f(v[j] - mrow);
    float rs = ((p[0] + p[1]) + (p[2] + p[3])) + ((p[4] + p[5]) + (p[6] + p[7]));
    rs += __shfl_xor(rs, 16);
    rs += __shfl_xor(rs, 32);
    lrow += rs;
    #pragma unroll
    for (int r = 0; r < 4; ++r) {
      lP[w][fr * PLD + fq * 4 + r]      = f2bf(p[r]);
      lP[w][fr * PLD + 16 + fq * 4 + r] = f2bf(p[4 + r]);
    }
  };

  auto pv = [&](f32x4* o, const bf16x8* vf) {
    u32x2 pa0 = *(const u32x2*)&lP[w][fr * PLD + fq * 8];
    u32x2 pa1 = *(const u32x2*)&lP[w][fr * PLD + fq * 8 + 4];
    u32x4 pc; pc[0] = pa0[0]; pc[1] = pa0[1]; pc[2] = pa1[0]; pc[3] = pa1[1];
    const bf16x8 pa = __builtin_bit_cast(bf16x8, pc);
    #pragma unroll
    for (int nb = 0; nb < 8; ++nb)
      o[nb] = __builtin_amdgcn_mfma_f32_16x16x32_bf16(pa, vf[nb], o[nb], 0, 0, 0);
  };

  // prologue: stage tile t0 into buffer 0
  stageK(0, t0 * KB);
  loadV(t0 * KB);
  writeV(0);

  for (int t = t0; t < t1; ++t) {
    const int kv0 = t * KB;
    const int cur = (t - t0) & 1, nxt = cur ^ 1;
    __syncthreads();   // drains vmcnt/lgkmcnt: lK[cur] DMA + lV[cur] writes visible
    if (t + 1 < t1) {
      stageK(nxt, kv0 + KB);   // async DMA, drained by next barrier
      loadV(kv0 + KB);         // regs; consumed by writeV after compute
    }

    const bool doA = (t < ntA);
    // SWAPPED QK^T: mfma(K, Q) -> lane owns one q-row's scores
    f32x4 sA0 = {}, sA1 = {}, sB0 = {}, sB1 = {};
    #pragma unroll
    for (int kk = 0; kk < 4; ++kk) {
      const int sl = ((kk * 4 + fq) ^ (fr & 7)) * 16;
      bf16x8 k0f = *(const bf16x8*)((const char*)&lK[cur][0] + fr * 256 + sl);
      bf16x8 k1f = *(const bf16x8*)((const char*)&lK[cur][0] + (16 + fr) * 256 + sl);
      if (doA) {
        sA0 = __builtin_amdgcn_mfma_f32_16x16x32_bf16(k0f, qfA[kk], sA0, 0, 0, 0);
        sA1 = __builtin_amdgcn_mfma_f32_16x16x32_bf16(k1f, qfA[kk], sA1, 0, 0, 0);
      }
      sB0 = __builtin_amdgcn_mfma_f32_16x16x32_bf16(k0f, qfB[kk], sB0, 0, 0, 0);
      sB1 = __builtin_amdgcn_mfma_f32_16x16x32_bf16(k1f, qfB[kk], sB1, 0, 0, 0);
    }

    bf16x8 vf[8];
    #pragma unroll
    for (int nb = 0; nb < 8; ++nb) {
      const u32 off = (((u32)(nb * 16 + fr) * 80) + (u32)fq * 16) ^ ((u32)nb << 4);
      vf[nb] = *(const bf16x8*)((const char*)&lV[cur][0] + off);
    }

    if (doA) { softmax_sw(sA0, sA1, mAs, lAs, oA, qA, kv0); pv(oA, vf); }
    softmax_sw(sB0, sB1, mBs, lBs, oB, qB, kv0);
    pv(oB, vf);

    if (t + 1 < t1) writeV(nxt);   // after compute
  }

  // epilogue: write UNNORMALIZED partials + (m,l) per row
  u16* po = split ? po1 : po0;
  float2* mlp = ml + (size_t)split * (B_ * H_ * S_) + (size_t)bh * S_;
  if (lane < 16) {
    mlp[qA + w * 16 + fr] = make_float2(mAs, lAs);
    mlp[qB + w * 16 + fr] = make_float2(mBs, lBs);
  }
  #pragma unroll
  for (int r = 0; r < 4; ++r) {
    const int rowA = qA + w * 16 + fq * 4 + r;
    const int rowB = qB + w * 16 + fq * 4 + r;
    u16* orA = po + base + (size_t)rowA * D_;
    u16* orB = po + base + (size_t)rowB * D_;
    #pragma unroll
    for (int nb = 0; nb < 8; ++nb) {
      orA[nb * 16 + fr] = f2bf(oA[nb][r]);
      orB[nb * 16 + fr] = f2bf(oB[nb][r]);
    }
  }
}

// ---------------- combine the 2 KV-splits ----------------
__global__ void attn_combine(const u16* __restrict__ po0, const u16* __restrict__ po1,
                             const float2* __restrict__ ml, u16* __restrict__ Og) {
  const int idx = blockIdx.x * blockDim.x + threadIdx.x;  // B*H*S*16
  const int d8 = (idx & 15) * 8;
  const int row = idx >> 4;            // bh*S + s
  const int bh = row >> 11, s = row & (S_ - 1);
  const float2 v0 = ml[row];
  const float2 v1 = ml[B_ * H_ * S_ + row];
  const float m = fmaxf(v0.x, v1.x);
  const float e0 = exp2f(v0.x - m), e1 = exp2f(v1.x - m);
  const float inv = 1.0f / (v0.y * e0 + v1.y * e1);
  const size_t off = (size_t)(bh >> 4) * S_ * D_ + (size_t)s * D_ + (bh & 15) * HD_ + d8;
  u16x8_t a = *(const u16x8_t*)(po0 + off);
  u16x8_t b = *(const u16x8_t*)(po1 + off);
  u16x8_t o;
  #pragma unroll
  for (int j = 0; j < 8; ++j)
    o[j] = f2bf((bf2f(a[j]) * e0 + bf2f(b[j]) * e1) * inv);
  *(u16x8_t*)(Og + off) = o;
}

// ---------------- launch ----------------
extern "C" void kernel_launch(void* const* d_in, const int* in_sizes, int n_in,
                              void* d_out, int out_size, void* d_ws, size_t ws_size,
                              hipStream_t stream) {
  const float* x  = (const float*)d_in[0];
  const float* Wq = (const float*)d_in[1];
  const float* Wk = (const float*)d_in[2];
  const float* Wv = (const float*)d_in[3];
  const float* Wo = (const float*)d_in[4];
  const int* pos  = (const int*)d_in[5];

  char* p = (char*)d_ws;
  u16* xb  = (u16*)p; p += (size_t)B_ * S_ * D_ * 2;
  u16* Wqb = (u16*)p; p += (size_t)D_ * D_ * 2;   // Wq/Wk/Wv contiguous -> packed [6144][2048]
  u16* Wkb = (u16*)p; p += (size_t)D_ * D_ * 2;
  u16* Wvb = (u16*)p; p += (size_t)D_ * D_ * 2;
  u16* Wob = (u16*)p; p += (size_t)D_ * D_ * 2;
  u16* Qb  = (u16*)p; p += (size_t)B_ * S_ * D_ * 2;
  u16* Kb  = (u16*)p; p += (size_t)B_ * S_ * D_ * 2;
  u16* Vb  = (u16*)p; p += (size_t)B_ * S_ * D_ * 2;
  float2* tab = (float2*)p; p += (size_t)S_ * 64 * sizeof(float2);
  float2* ml  = (float2*)p; p += (size_t)2 * B_ * H_ * S_ * sizeof(float2);
  // partial-O buffers reuse dead regions (xb, Wqb+Wkb dead after gemm_qkv3)
  u16* po0 = xb;
  u16* po1 = Wqb;
  u16* Ob  = Qb;  // combined attention output overwrites Q (attn reads Q first)

  cvt_all<<<24576, 256, 0, stream>>>(x, Wq, Wk, Wv, Wo, xb);
  rope_table<<<(S_ * 64) / 256, 256, 0, stream>>>(pos, tab);

  // fused QKV projection: 128x256 tiles, grid (32,24)=768 blocks
  gemm_qkv3<<<dim3(B_ * S_ / 128, 24), 256, 0, stream>>>(xb, Wqb, Qb, Kb, Vb);

  // standalone K-RoPE (Q roped in-register inside attn)
  rope_k<<<(B_ * S_ * H_ * 16) / 256, 256, 0, stream>>>(Kb, tab);

  // KV-split flash attention + combine
  attn_fwd<<<dim3(16, B_ * H_, 2), 256, 0, stream>>>(Qb, Kb, Vb, tab, po0, po1, ml);
  attn_combine<<<(B_ * H_ * S_ * 16) / 256, 256, 0, stream>>>(po0, po1, ml, Ob);

  gemm_bt<true><<<dim3(B_ * S_ / 128, D_ / 128), 256, 0, stream>>>(Ob, Wob, (float*)d_out, B_ * S_, D_, D_);
}

// Round 17
// 314.033 us; speedup vs baseline: 2.8952x; 1.0638x over previous
//
#include <hip/hip_runtime.h>
#include <math.h>

// Problem constants
#define B_  2
#define S_  2048
#define D_  2048
#define H_  16
#define HD_ 128

using u16 = unsigned short;
using u32 = unsigned int;
typedef __attribute__((ext_vector_type(4))) float f32x4;
typedef __attribute__((ext_vector_type(8))) short bf16x8;   // 8 bf16 = 4 VGPRs (MFMA A/B frag)
using u16x4_t = __attribute__((ext_vector_type(4))) unsigned short;
using u16x8_t = __attribute__((ext_vector_type(8))) unsigned short;
typedef __attribute__((ext_vector_type(2))) u32 u32x2;
typedef __attribute__((ext_vector_type(4))) u32 u32x4;

__device__ __forceinline__ u16 f2bf(float f) {
  u32 u = __builtin_bit_cast(u32, f);
  u32 r = u + 0x7fffu + ((u >> 16) & 1u);   // RNE
  return (u16)(r >> 16);
}
__device__ __forceinline__ float bf2f(u16 x) {
  u32 u = ((u32)x) << 16;
  return __builtin_bit_cast(float, u);
}
// async global->LDS, 16B per lane; LDS dest = wave-uniform base + lane*16;
// global source address is PER-LANE (enables source-side swizzling).
__device__ __forceinline__ void async_copy16(const u16* g, u16* l) {
  __builtin_amdgcn_global_load_lds((const __attribute__((address_space(1))) u32*)g,
                                   (__attribute__((address_space(3))) u32*)l, 16, 0, 0);
}

// ---------------- fused fp32 -> bf16 convert (x, Wq, Wk, Wv, Wo in one pass) ----------------
__global__ void cvt_all(const float* __restrict__ x, const float* __restrict__ Wq,
                        const float* __restrict__ Wk, const float* __restrict__ Wv,
                        const float* __restrict__ Wo, u16* __restrict__ dst) {
  const int i = (blockIdx.x * blockDim.x + threadIdx.x) * 4;
  if (i >= 25165824) return;
  const float* src;
  int off;
  if (i < (1 << 23)) { src = x; off = i; }
  else {
    const int wi = i - (1 << 23);
    const int which = wi >> 22;
    off = wi & ((1 << 22) - 1);
    src = (which == 0) ? Wq : (which == 1) ? Wk : (which == 2) ? Wv : Wo;
  }
  float4 v = *(const float4*)(src + off);
  u16x4_t o;
  o[0] = f2bf(v.x); o[1] = f2bf(v.y); o[2] = f2bf(v.z); o[3] = f2bf(v.w);
  *(u16x4_t*)(dst + i) = o;
}

// ---------------- RoPE cos/sin table ----------------
__global__ void rope_table(const int* __restrict__ pos, float2* __restrict__ tab) {
  int t = blockIdx.x * blockDim.x + threadIdx.x;  // S*64
  if (t >= S_ * 64) return;
  int s = t >> 6, i = t & 63;
  float freq = expf(-(float)i * (9.210340371976184f / 64.0f));  // theta^{-i/64}
  float ang = (float)pos[s] * freq;
  tab[t] = make_float2(cosf(ang), sinf(ang));
}

// ---------------- K-only RoPE (proven standalone) ----------------
__global__ void rope_k(u16* __restrict__ K, const float2* __restrict__ tab) {
  int t = blockIdx.x * blockDim.x + threadIdx.x;  // B*S*H*16
  int g = t & 15;
  int bsh = t >> 4;
  int h = bsh & (H_ - 1);
  int bs = bsh >> 4;            // b*S + s
  int s = bs & (S_ - 1);
  size_t base = (size_t)bs * D_ + (size_t)h * HD_;
  int d2 = g * 4;
  const float2* tb = &tab[s * 64 + d2];
  float2 cs[4];
  #pragma unroll
  for (int j = 0; j < 4; ++j) cs[j] = tb[j];
  u16x4_t a = *(u16x4_t*)(K + base + d2);
  u16x4_t c = *(u16x4_t*)(K + base + 64 + d2);
  u16x4_t ra, rc;
  #pragma unroll
  for (int j = 0; j < 4; ++j) {
    float t1 = bf2f(a[j]), t2 = bf2f(c[j]);
    ra[j] = f2bf(t1 * cs[j].x - t2 * cs[j].y);
    rc[j] = f2bf(t1 * cs[j].y + t2 * cs[j].x);
  }
  *(u16x4_t*)(K + base + d2) = ra;
  *(u16x4_t*)(K + base + 64 + d2) = rc;
}

// ---------------- GEMM: C = A(MxK) * Bt(NxK)^T (128x128, round-10 proven) ----------------
// Triple-buffered LDS, counted vmcnt(4), both-sides slot swizzle (0 conflicts),
// 1 raw s_barrier per K-step. 128x128 tile confirmed optimal for this structure
// (r16: 128x256 at 2 blocks/CU lost 15 us -> m105/m112 pattern).
template <bool F32OUT>
__global__ __launch_bounds__(256, 2)
void gemm_bt(const u16* __restrict__ A, const u16* __restrict__ Bt,
             void* __restrict__ Cout, int M, int N, int K) {
  __shared__ u16 lA[3][128 * 32];
  __shared__ u16 lB[3][128 * 32];
  const int tid = threadIdx.x;
  const int lane = tid & 63;
  const int w = tid >> 6;            // wave 0..3
  const int wr = w >> 1, wc = w & 1; // 2x2 waves of 64x64
  const int bm = blockIdx.x * 128;
  const int bn = blockIdx.y * 128;
  const int fr = lane & 15, fq = lane >> 4;
  const int KT = K >> 5;
  f32x4 acc[4][4] = {};

  auto stage = [&](int buf, int kt) {
    const int k0 = kt << 5;
    #pragma unroll
    for (int c = w; c < 8; c += 4) {
      const int r = c * 16 + (lane >> 2);
      const int col = ((lane & 3) ^ ((r >> 1) & 3)) * 8;   // pre-swizzled source slot
      async_copy16(A + (size_t)(bm + r) * K + k0 + col, &lA[buf][c * 512]);
      async_copy16(Bt + (size_t)(bn + r) * K + k0 + col, &lB[buf][c * 512]);
    }
  };

  stage(0, 0);
  stage(1, 1);
  asm volatile("s_waitcnt vmcnt(4)" ::: "memory");   // tile 0 landed; tile 1 in flight
  __builtin_amdgcn_s_barrier();
  asm volatile("" ::: "memory");

  int p = 0, sb = 2;
  #pragma unroll 1
  for (int kt = 0; kt < KT; ++kt) {
    if (kt + 2 < KT) stage(sb, kt + 2);
    bf16x8 af[4], bfr[4];
    #pragma unroll
    for (int i = 0; i < 4; ++i) {
      const int ra = wr * 64 + i * 16 + fr;
      const int rb = wc * 64 + i * 16 + fr;
      af[i]  = *(const bf16x8*)&lA[p][ra * 32 + ((fq ^ ((ra >> 1) & 3)) * 8)];
      bfr[i] = *(const bf16x8*)&lB[p][rb * 32 + ((fq ^ ((rb >> 1) & 3)) * 8)];
    }
    #pragma unroll
    for (int i = 0; i < 4; ++i)
      #pragma unroll
      for (int j = 0; j < 4; ++j)
        acc[i][j] = __builtin_amdgcn_mfma_f32_16x16x32_bf16(af[i], bfr[j], acc[i][j], 0, 0, 0);
    if (kt + 1 < KT) {
      if (kt + 2 < KT) asm volatile("s_waitcnt vmcnt(4)" ::: "memory");  // kt+1 landed
      else             asm volatile("s_waitcnt vmcnt(0)" ::: "memory");  // tail drain
      __builtin_amdgcn_s_barrier();
      asm volatile("" ::: "memory");
    }
    p  = (p == 2) ? 0 : p + 1;
    sb = (sb == 2) ? 0 : sb + 1;
  }
  // C/D layout: col = lane&15, row = (lane>>4)*4 + reg  [m89/m91 verified]
  #pragma unroll
  for (int i = 0; i < 4; ++i)
    #pragma unroll
    for (int j = 0; j < 4; ++j) {
      const int row = bm + wr * 64 + i * 16 + fq * 4;
      const int col = bn + wc * 64 + j * 16 + fr;
      #pragma unroll
      for (int r = 0; r < 4; ++r) {
        const float v = acc[i][j][r];
        if (F32OUT) ((float*)Cout)[(size_t)(row + r) * N + col] = v;
        else        ((u16*)Cout)[(size_t)(row + r) * N + col] = f2bf(v);
      }
    }
}

// ---------------- fused QKV GEMM: Bt packed [6144][2048] (Wq;Wk;Wv) ----------------
// Round-14 proven 128x128 body (132.7 us) + launch_bounds guard. Output routed
// by bn>>11. Grid (32,48) = 1536 blocks.
__global__ __launch_bounds__(256, 2)
void gemm_qkv3(const u16* __restrict__ A, const u16* __restrict__ Bt,
               u16* __restrict__ Qo, u16* __restrict__ Ko, u16* __restrict__ Vo) {
  __shared__ u16 lA[3][128 * 32];
  __shared__ u16 lB[3][128 * 32];
  const int tid = threadIdx.x;
  const int lane = tid & 63;
  const int w = tid >> 6;
  const int wr = w >> 1, wc = w & 1;
  const int bm = blockIdx.x * 128;
  const int bn = blockIdx.y * 128;          // 0..6016
  const int fr = lane & 15, fq = lane >> 4;
  const int K = D_;
  const int KT = K >> 5;                    // 64
  f32x4 acc[4][4] = {};

  auto stage = [&](int buf, int kt) {
    const int k0 = kt << 5;
    #pragma unroll
    for (int c = w; c < 8; c += 4) {
      const int r = c * 16 + (lane >> 2);
      const int col = ((lane & 3) ^ ((r >> 1) & 3)) * 8;
      async_copy16(A + (size_t)(bm + r) * K + k0 + col, &lA[buf][c * 512]);
      async_copy16(Bt + (size_t)(bn + r) * K + k0 + col, &lB[buf][c * 512]);
    }
  };

  stage(0, 0);
  stage(1, 1);
  asm volatile("s_waitcnt vmcnt(4)" ::: "memory");
  __builtin_amdgcn_s_barrier();
  asm volatile("" ::: "memory");

  int p = 0, sb = 2;
  #pragma unroll 1
  for (int kt = 0; kt < KT; ++kt) {
    if (kt + 2 < KT) stage(sb, kt + 2);
    bf16x8 af[4], bfr[4];
    #pragma unroll
    for (int i = 0; i < 4; ++i) {
      const int ra = wr * 64 + i * 16 + fr;
      const int rb = wc * 64 + i * 16 + fr;
      af[i]  = *(const bf16x8*)&lA[p][ra * 32 + ((fq ^ ((ra >> 1) & 3)) * 8)];
      bfr[i] = *(const bf16x8*)&lB[p][rb * 32 + ((fq ^ ((rb >> 1) & 3)) * 8)];
    }
    #pragma unroll
    for (int i = 0; i < 4; ++i)
      #pragma unroll
      for (int j = 0; j < 4; ++j)
        acc[i][j] = __builtin_amdgcn_mfma_f32_16x16x32_bf16(af[i], bfr[j], acc[i][j], 0, 0, 0);
    if (kt + 1 < KT) {
      if (kt + 2 < KT) asm volatile("s_waitcnt vmcnt(4)" ::: "memory");
      else             asm volatile("s_waitcnt vmcnt(0)" ::: "memory");
      __builtin_amdgcn_s_barrier();
      asm volatile("" ::: "memory");
    }
    p  = (p == 2) ? 0 : p + 1;
    sb = (sb == 2) ? 0 : sb + 1;
  }
  u16* out = (bn < 2048) ? Qo : (bn < 4096) ? Ko : Vo;
  const int bnl = bn & 2047;
  #pragma unroll
  for (int i = 0; i < 4; ++i)
    #pragma unroll
    for (int j = 0; j < 4; ++j) {
      const int row = bm + wr * 64 + i * 16 + fq * 4;
      const int col = bnl + wc * 64 + j * 16 + fr;
      #pragma unroll
      for (int r = 0; r < 4; ++r)
        out[(size_t)(row + r) * D_ + col] = f2bf(acc[i][j][r]);
    }
}

// ---------------- causal flash attention, KV-split + swapped-QK softmax + Q-RoPE ----------------
// + defer-max (T13, THR=12). NaN-safe: first processed tile of each
// (q-tile,split) is fully unmasked -> mrow finite before any fully-masked row.
#define QB 64
#define KB 32
#define PLD 36    // P row stride (72B): [q][kv] layout; b64 reads aligned

__global__ __launch_bounds__(256, 2)
void attn_fwd(const u16* __restrict__ Qg, const u16* __restrict__ Kg,
              const u16* __restrict__ Vg, const float2* __restrict__ tab,
              u16* __restrict__ po0, u16* __restrict__ po1, float2* __restrict__ ml) {
  __shared__ u16 lK[2][KB * HD_];   // linear [kv][hd], source-swizzled content
  __shared__ u16 lV[2][HD_ * 40];   // swizzled V^T
  __shared__ u16 lP[4][16 * PLD];   // per-wave P 16x32, [q][kv]
  const int tid = threadIdx.x;
  const int lane = tid & 63;
  const int w = tid >> 6;
  const int fr = lane & 15, fq = lane >> 4;
  const int xA = blockIdx.x;                 // 0..15
  const int bh = blockIdx.y;
  const int split = blockIdx.z;
  const size_t base = (size_t)(bh >> 4) * S_ * D_ + (size_t)(bh & 15) * HD_;
  const int qA = xA * QB, qB = (31 - xA) * QB;
  const int ntA = (qA + QB) / KB;            // 2..32
  const int ntB = (qB + QB) / KB;            // 34..64
  const int c = (ntA <= 16) ? (33 - ntA) : 16;   // balanced split point
  const int t0 = split ? c : 0;
  const int t1 = split ? ntB : c;
  const float kscale = 0.08838834764831843f * 1.4426950408889634f; // 1/sqrt(128)*log2e

  // Q fragments for both q-tiles (row=lane&15 -> q, k=(lane>>4)*8+j -> hd)
  bf16x8 qfA[4], qfB[4];
  {
    const u16* qpa = Qg + base + (size_t)(qA + w * 16 + fr) * D_ + fq * 8;
    const u16* qpb = Qg + base + (size_t)(qB + w * 16 + fr) * D_ + fq * 8;
    #pragma unroll
    for (int kk = 0; kk < 4; ++kk) {
      qfA[kk] = *(const bf16x8*)(qpa + kk * 32);
      qfB[kk] = *(const bf16x8*)(qpb + kk * 32);
    }
    // in-register Q-RoPE: d2 = kk*32 + fq*8 + j pairs with d2+64 (kk+2)
    const float2* tA = &tab[(qA + w * 16 + fr) * 64 + fq * 8];
    const float2* tB = &tab[(qB + w * 16 + fr) * 64 + fq * 8];
    #pragma unroll
    for (int kk = 0; kk < 2; ++kk)
      #pragma unroll
      for (int j = 0; j < 8; ++j) {
        const float2 ca = tA[kk * 32 + j];
        float t1 = bf2f((u16)qfA[kk][j]), t2 = bf2f((u16)qfA[kk + 2][j]);
        qfA[kk][j]     = (short)f2bf(t1 * ca.x - t2 * ca.y);
        qfA[kk + 2][j] = (short)f2bf(t1 * ca.y + t2 * ca.x);
        const float2 cb = tB[kk * 32 + j];
        t1 = bf2f((u16)qfB[kk][j]); t2 = bf2f((u16)qfB[kk + 2][j]);
        qfB[kk][j]     = (short)f2bf(t1 * cb.x - t2 * cb.y);
        qfB[kk + 2][j] = (short)f2bf(t1 * cb.y + t2 * cb.x);
      }
  }
  f32x4 oA[8] = {}, oB[8] = {};
  float mAs = -INFINITY, lAs = 0.f, mBs = -INFINITY, lBs = 0.f;

  auto stageK = [&](int buf, int kv0) {
    #pragma unroll
    for (int cc = w; cc < 8; cc += 4) {
      const int row = cc * 4 + (lane >> 4);
      const int slot = (lane & 15) ^ (row & 7);
      async_copy16(Kg + base + (size_t)(kv0 + row) * D_ + slot * 8, &lK[buf][cc * 512]);
    }
  };
  const int srow = tid >> 3, sc0 = (tid & 7) * 16;
  const u32 swz = (u32)((sc0 >> 4) & 7) << 4;
  const u32 rb = (u32)srow * 2;
  u16x8_t rv0, rv1;
  auto loadV = [&](int kv0) {
    const u16* gv = Vg + base + (size_t)(kv0 + srow) * D_ + sc0;
    rv0 = *(const u16x8_t*)gv; rv1 = *(const u16x8_t*)(gv + 8);
  };
  auto writeV = [&](int buf) {
    char* lv = (char*)&lV[buf][0];
    #pragma unroll
    for (int j = 0; j < 8; ++j) {
      *(u16*)(lv + ((((u32)(sc0 + j) * 80) + rb) ^ swz))     = rv0[j];
      *(u16*)(lv + ((((u32)(sc0 + 8 + j) * 80) + rb) ^ swz)) = rv1[j];
    }
  };

  // swapped-layout softmax + defer-max: lane owns q=fr's row, kv slots fq*4+r (+16c)
  auto softmax_sw = [&](const f32x4& s0, const f32x4& s1, float& mrow, float& lrow,
                        f32x4* o, int q0t, int kv0) {
    const int qg = q0t + w * 16 + fr;
    const bool notfull = (kv0 + KB - 1 > q0t);
    float v[8];
    #pragma unroll
    for (int r = 0; r < 4; ++r) {
      v[r]     = s0[r] * kscale;
      v[4 + r] = s1[r] * kscale;
      if (notfull) {
        if (kv0 + fq * 4 + r > qg)      v[r]     = -INFINITY;
        if (kv0 + 16 + fq * 4 + r > qg) v[4 + r] = -INFINITY;
      }
    }
    float mx = fmaxf(fmaxf(fmaxf(v[0], v[1]), fmaxf(v[2], v[3])),
                     fmaxf(fmaxf(v[4], v[5]), fmaxf(v[6], v[7])));
    mx = fmaxf(mx, __shfl_xor(mx, 16));
    mx = fmaxf(mx, __shfl_xor(mx, 32));
    // T13 defer-max: rescale only when some row's max grew by > 12 log2 units
    const int nogrow = (mx <= mrow + 12.f);
    if (!__all(nogrow)) {
      const float mn = fmaxf(mrow, mx);
      const float al = exp2f(mrow - mn);
      mrow = mn;
      lrow *= al;
      #pragma unroll
      for (int r = 0; r < 4; ++r) {
        const float ab = __shfl(al, fq * 4 + r);
        #pragma unroll
        for (int nb = 0; nb < 8; ++nb) o[nb][r] *= ab;
      }
    }
    float p[8];
    #pragma unroll
    for (int j = 0; j < 8; ++j) p[j] = exp2f(v[j] - mrow);
    float rs = ((p[0] + p[1]) + (p[2] + p[3])) + ((p[4] + p[5]) + (p[6] + p[7]));
    rs += __shfl_xor(rs, 16);
    rs += __shfl_xor(rs, 32);
    lrow += rs;
    #pragma unroll
    for (int r = 0; r < 4; ++r) {
      lP[w][fr * PLD + fq * 4 + r]      = f2bf(p[r]);
      lP[w][fr * PLD + 16 + fq * 4 + r] = f2bf(p[4 + r]);
    }
  };

  auto pv = [&](f32x4* o, const bf16x8* vf) {
    u32x2 pa0 = *(const u32x2*)&lP[w][fr * PLD + fq * 8];
    u32x2 pa1 = *(const u32x2*)&lP[w][fr * PLD + fq * 8 + 4];
    u32x4 pc; pc[0] = pa0[0]; pc[1] = pa0[1]; pc[2] = pa1[0]; pc[3] = pa1[1];
    const bf16x8 pa = __builtin_bit_cast(bf16x8, pc);
    #pragma unroll
    for (int nb = 0; nb < 8; ++nb)
      o[nb] = __builtin_amdgcn_mfma_f32_16x16x32_bf16(pa, vf[nb], o[nb], 0, 0, 0);
  };

  // prologue: stage tile t0 into buffer 0
  stageK(0, t0 * KB);
  loadV(t0 * KB);
  writeV(0);

  for (int t = t0; t < t1; ++t) {
    const int kv0 = t * KB;
    const int cur = (t - t0) & 1, nxt = cur ^ 1;
    __syncthreads();   // drains vmcnt/lgkmcnt: lK[cur] DMA + lV[cur] writes visible
    if (t + 1 < t1) {
      stageK(nxt, kv0 + KB);   // async DMA, drained by next barrier
      loadV(kv0 + KB);         // regs; consumed by writeV after compute
    }

    const bool doA = (t < ntA);
    // SWAPPED QK^T: mfma(K, Q) -> lane owns one q-row's scores
    f32x4 sA0 = {}, sA1 = {}, sB0 = {}, sB1 = {};
    #pragma unroll
    for (int kk = 0; kk < 4; ++kk) {
      const int sl = ((kk * 4 + fq) ^ (fr & 7)) * 16;
      bf16x8 k0f = *(const bf16x8*)((const char*)&lK[cur][0] + fr * 256 + sl);
      bf16x8 k1f = *(const bf16x8*)((const char*)&lK[cur][0] + (16 + fr) * 256 + sl);
      if (doA) {
        sA0 = __builtin_amdgcn_mfma_f32_16x16x32_bf16(k0f, qfA[kk], sA0, 0, 0, 0);
        sA1 = __builtin_amdgcn_mfma_f32_16x16x32_bf16(k1f, qfA[kk], sA1, 0, 0, 0);
      }
      sB0 = __builtin_amdgcn_mfma_f32_16x16x32_bf16(k0f, qfB[kk], sB0, 0, 0, 0);
      sB1 = __builtin_amdgcn_mfma_f32_16x16x32_bf16(k1f, qfB[kk], sB1, 0, 0, 0);
    }

    bf16x8 vf[8];
    #pragma unroll
    for (int nb = 0; nb < 8; ++nb) {
      const u32 off = (((u32)(nb * 16 + fr) * 80) + (u32)fq * 16) ^ ((u32)nb << 4);
      vf[nb] = *(const bf16x8*)((const char*)&lV[cur][0] + off);
    }

    if (doA) { softmax_sw(sA0, sA1, mAs, lAs, oA, qA, kv0); pv(oA, vf); }
    softmax_sw(sB0, sB1, mBs, lBs, oB, qB, kv0);
    pv(oB, vf);

    if (t + 1 < t1) writeV(nxt);   // after compute
  }

  // epilogue: write UNNORMALIZED partials + (m,l) per row
  u16* po = split ? po1 : po0;
  float2* mlp = ml + (size_t)split * (B_ * H_ * S_) + (size_t)bh * S_;
  if (lane < 16) {
    mlp[qA + w * 16 + fr] = make_float2(mAs, lAs);
    mlp[qB + w * 16 + fr] = make_float2(mBs, lBs);
  }
  #pragma unroll
  for (int r = 0; r < 4; ++r) {
    const int rowA = qA + w * 16 + fq * 4 + r;
    const int rowB = qB + w * 16 + fq * 4 + r;
    u16* orA = po + base + (size_t)rowA * D_;
    u16* orB = po + base + (size_t)rowB * D_;
    #pragma unroll
    for (int nb = 0; nb < 8; ++nb) {
      orA[nb * 16 + fr] = f2bf(oA[nb][r]);
      orB[nb * 16 + fr] = f2bf(oB[nb][r]);
    }
  }
}

// ---------------- combine the 2 KV-splits ----------------
__global__ void attn_combine(const u16* __restrict__ po0, const u16* __restrict__ po1,
                             const float2* __restrict__ ml, u16* __restrict__ Og) {
  const int idx = blockIdx.x * blockDim.x + threadIdx.x;  // B*H*S*16
  const int d8 = (idx & 15) * 8;
  const int row = idx >> 4;            // bh*S + s
  const int bh = row >> 11, s = row & (S_ - 1);
  const float2 v0 = ml[row];
  const float2 v1 = ml[B_ * H_ * S_ + row];
  const float m = fmaxf(v0.x, v1.x);
  const float e0 = exp2f(v0.x - m), e1 = exp2f(v1.x - m);
  const float inv = 1.0f / (v0.y * e0 + v1.y * e1);
  const size_t off = (size_t)(bh >> 4) * S_ * D_ + (size_t)s * D_ + (bh & 15) * HD_ + d8;
  u16x8_t a = *(const u16x8_t*)(po0 + off);
  u16x8_t b = *(const u16x8_t*)(po1 + off);
  u16x8_t o;
  #pragma unroll
  for (int j = 0; j < 8; ++j)
    o[j] = f2bf((bf2f(a[j]) * e0 + bf2f(b[j]) * e1) * inv);
  *(u16x8_t*)(Og + off) = o;
}

// ---------------- launch ----------------
extern "C" void kernel_launch(void* const* d_in, const int* in_sizes, int n_in,
                              void* d_out, int out_size, void* d_ws, size_t ws_size,
                              hipStream_t stream) {
  const float* x  = (const float*)d_in[0];
  const float* Wq = (const float*)d_in[1];
  const float* Wk = (const float*)d_in[2];
  const float* Wv = (const float*)d_in[3];
  const float* Wo = (const float*)d_in[4];
  const int* pos  = (const int*)d_in[5];

  char* p = (char*)d_ws;
  u16* xb  = (u16*)p; p += (size_t)B_ * S_ * D_ * 2;
  u16* Wqb = (u16*)p; p += (size_t)D_ * D_ * 2;   // Wq/Wk/Wv contiguous -> packed [6144][2048]
  u16* Wkb = (u16*)p; p += (size_t)D_ * D_ * 2;
  u16* Wvb = (u16*)p; p += (size_t)D_ * D_ * 2;
  u16* Wob = (u16*)p; p += (size_t)D_ * D_ * 2;
  u16* Qb  = (u16*)p; p += (size_t)B_ * S_ * D_ * 2;
  u16* Kb  = (u16*)p; p += (size_t)B_ * S_ * D_ * 2;
  u16* Vb  = (u16*)p; p += (size_t)B_ * S_ * D_ * 2;
  float2* tab = (float2*)p; p += (size_t)S_ * 64 * sizeof(float2);
  float2* ml  = (float2*)p; p += (size_t)2 * B_ * H_ * S_ * sizeof(float2);
  // partial-O buffers reuse dead regions (xb, Wqb+Wkb dead after gemm_qkv3)
  u16* po0 = xb;
  u16* po1 = Wqb;
  u16* Ob  = Qb;  // combined attention output overwrites Q (attn reads Q first)

  cvt_all<<<24576, 256, 0, stream>>>(x, Wq, Wk, Wv, Wo, xb);
  rope_table<<<(S_ * 64) / 256, 256, 0, stream>>>(pos, tab);

  // fused QKV projection: 128x128 tiles (proven optimum), grid (32,48)
  gemm_qkv3<<<dim3(B_ * S_ / 128, 48), 256, 0, stream>>>(xb, Wqb, Qb, Kb, Vb);

  // standalone K-RoPE (Q roped in-register inside attn)
  rope_k<<<(B_ * S_ * H_ * 16) / 256, 256, 0, stream>>>(Kb, tab);

  // KV-split flash attention + combine
  attn_fwd<<<dim3(16, B_ * H_, 2), 256, 0, stream>>>(Qb, Kb, Vb, tab, po0, po1, ml);
  attn_combine<<<(B_ * H_ * S_ * 16) / 256, 256, 0, stream>>>(po0, po1, ml, Ob);

  gemm_bt<true><<<dim3(B_ * S_ / 128, D_ / 128), 256, 0, stream>>>(Ob, Wob, (float*)d_out, B_ * S_, D_, D_);
}

// Round 18
// 295.793 us; speedup vs baseline: 3.0737x; 1.0617x over previous
//
#include <hip/hip_runtime.h>
#include <math.h>

// Problem constants
#define B_  2
#define S_  2048
#define D_  2048
#define H_  16
#define HD_ 128

using u16 = unsigned short;
using u32 = unsigned int;
typedef __attribute__((ext_vector_type(4))) float f32x4;
typedef __attribute__((ext_vector_type(8))) short bf16x8;   // 8 bf16 = 4 VGPRs (MFMA A/B frag)
using u16x4_t = __attribute__((ext_vector_type(4))) unsigned short;
using u16x8_t = __attribute__((ext_vector_type(8))) unsigned short;
typedef __attribute__((ext_vector_type(2))) u32 u32x2;
typedef __attribute__((ext_vector_type(4))) u32 u32x4;

__device__ __forceinline__ u16 f2bf(float f) {
  u32 u = __builtin_bit_cast(u32, f);
  u32 r = u + 0x7fffu + ((u >> 16) & 1u);   // RNE
  return (u16)(r >> 16);
}
__device__ __forceinline__ float bf2f(u16 x) {
  u32 u = ((u32)x) << 16;
  return __builtin_bit_cast(float, u);
}
// async global->LDS, 16B per lane; LDS dest = wave-uniform base + lane*16;
// global source address is PER-LANE (enables source-side swizzling).
__device__ __forceinline__ void async_copy16(const u16* g, u16* l) {
  __builtin_amdgcn_global_load_lds((const __attribute__((address_space(1))) u32*)g,
                                   (__attribute__((address_space(3))) u32*)l, 16, 0, 0);
}

// ---------------- fused fp32 -> bf16 convert (x, Wq, Wk, Wv, Wo in one pass) ----------------
__global__ void cvt_all(const float* __restrict__ x, const float* __restrict__ Wq,
                        const float* __restrict__ Wk, const float* __restrict__ Wv,
                        const float* __restrict__ Wo, u16* __restrict__ dst) {
  const int i = (blockIdx.x * blockDim.x + threadIdx.x) * 4;
  if (i >= 25165824) return;
  const float* src;
  int off;
  if (i < (1 << 23)) { src = x; off = i; }
  else {
    const int wi = i - (1 << 23);
    const int which = wi >> 22;
    off = wi & ((1 << 22) - 1);
    src = (which == 0) ? Wq : (which == 1) ? Wk : (which == 2) ? Wv : Wo;
  }
  float4 v = *(const float4*)(src + off);
  u16x4_t o;
  o[0] = f2bf(v.x); o[1] = f2bf(v.y); o[2] = f2bf(v.z); o[3] = f2bf(v.w);
  *(u16x4_t*)(dst + i) = o;
}

// ---------------- RoPE cos/sin table ----------------
__global__ void rope_table(const int* __restrict__ pos, float2* __restrict__ tab) {
  int t = blockIdx.x * blockDim.x + threadIdx.x;  // S*64
  if (t >= S_ * 64) return;
  int s = t >> 6, i = t & 63;
  float freq = expf(-(float)i * (9.210340371976184f / 64.0f));  // theta^{-i/64}
  float ang = (float)pos[s] * freq;
  tab[t] = make_float2(cosf(ang), sinf(ang));
}

// ---------------- K-only RoPE (proven standalone) ----------------
__global__ void rope_k(u16* __restrict__ K, const float2* __restrict__ tab) {
  int t = blockIdx.x * blockDim.x + threadIdx.x;  // B*S*H*16
  int g = t & 15;
  int bsh = t >> 4;
  int h = bsh & (H_ - 1);
  int bs = bsh >> 4;            // b*S + s
  int s = bs & (S_ - 1);
  size_t base = (size_t)bs * D_ + (size_t)h * HD_;
  int d2 = g * 4;
  const float2* tb = &tab[s * 64 + d2];
  float2 cs[4];
  #pragma unroll
  for (int j = 0; j < 4; ++j) cs[j] = tb[j];
  u16x4_t a = *(u16x4_t*)(K + base + d2);
  u16x4_t c = *(u16x4_t*)(K + base + 64 + d2);
  u16x4_t ra, rc;
  #pragma unroll
  for (int j = 0; j < 4; ++j) {
    float t1 = bf2f(a[j]), t2 = bf2f(c[j]);
    ra[j] = f2bf(t1 * cs[j].x - t2 * cs[j].y);
    rc[j] = f2bf(t1 * cs[j].y + t2 * cs[j].x);
  }
  *(u16x4_t*)(K + base + d2) = ra;
  *(u16x4_t*)(K + base + 64 + d2) = rc;
}

// ---------------- GEMM: C = A(MxK) * Bt(NxK)^T (128x128, round-10 proven) ----------------
template <bool F32OUT>
__global__ __launch_bounds__(256, 2)
void gemm_bt(const u16* __restrict__ A, const u16* __restrict__ Bt,
             void* __restrict__ Cout, int M, int N, int K) {
  __shared__ u16 lA[3][128 * 32];
  __shared__ u16 lB[3][128 * 32];
  const int tid = threadIdx.x;
  const int lane = tid & 63;
  const int w = tid >> 6;            // wave 0..3
  const int wr = w >> 1, wc = w & 1; // 2x2 waves of 64x64
  const int bm = blockIdx.x * 128;
  const int bn = blockIdx.y * 128;
  const int fr = lane & 15, fq = lane >> 4;
  const int KT = K >> 5;
  f32x4 acc[4][4] = {};

  auto stage = [&](int buf, int kt) {
    const int k0 = kt << 5;
    #pragma unroll
    for (int c = w; c < 8; c += 4) {
      const int r = c * 16 + (lane >> 2);
      const int col = ((lane & 3) ^ ((r >> 1) & 3)) * 8;   // pre-swizzled source slot
      async_copy16(A + (size_t)(bm + r) * K + k0 + col, &lA[buf][c * 512]);
      async_copy16(Bt + (size_t)(bn + r) * K + k0 + col, &lB[buf][c * 512]);
    }
  };

  stage(0, 0);
  stage(1, 1);
  asm volatile("s_waitcnt vmcnt(4)" ::: "memory");   // tile 0 landed; tile 1 in flight
  __builtin_amdgcn_s_barrier();
  asm volatile("" ::: "memory");

  int p = 0, sb = 2;
  #pragma unroll 1
  for (int kt = 0; kt < KT; ++kt) {
    if (kt + 2 < KT) stage(sb, kt + 2);
    bf16x8 af[4], bfr[4];
    #pragma unroll
    for (int i = 0; i < 4; ++i) {
      const int ra = wr * 64 + i * 16 + fr;
      const int rb = wc * 64 + i * 16 + fr;
      af[i]  = *(const bf16x8*)&lA[p][ra * 32 + ((fq ^ ((ra >> 1) & 3)) * 8)];
      bfr[i] = *(const bf16x8*)&lB[p][rb * 32 + ((fq ^ ((rb >> 1) & 3)) * 8)];
    }
    #pragma unroll
    for (int i = 0; i < 4; ++i)
      #pragma unroll
      for (int j = 0; j < 4; ++j)
        acc[i][j] = __builtin_amdgcn_mfma_f32_16x16x32_bf16(af[i], bfr[j], acc[i][j], 0, 0, 0);
    if (kt + 1 < KT) {
      if (kt + 2 < KT) asm volatile("s_waitcnt vmcnt(4)" ::: "memory");  // kt+1 landed
      else             asm volatile("s_waitcnt vmcnt(0)" ::: "memory");  // tail drain
      __builtin_amdgcn_s_barrier();
      asm volatile("" ::: "memory");
    }
    p  = (p == 2) ? 0 : p + 1;
    sb = (sb == 2) ? 0 : sb + 1;
  }
  // C/D layout: col = lane&15, row = (lane>>4)*4 + reg  [m89/m91 verified]
  #pragma unroll
  for (int i = 0; i < 4; ++i)
    #pragma unroll
    for (int j = 0; j < 4; ++j) {
      const int row = bm + wr * 64 + i * 16 + fq * 4;
      const int col = bn + wc * 64 + j * 16 + fr;
      #pragma unroll
      for (int r = 0; r < 4; ++r) {
        const float v = acc[i][j][r];
        if (F32OUT) ((float*)Cout)[(size_t)(row + r) * N + col] = v;
        else        ((u16*)Cout)[(size_t)(row + r) * N + col] = f2bf(v);
      }
    }
}

// ---------------- fused QKV GEMM: Bt packed [6144][2048] (Wq;Wk;Wv) ----------------
__global__ __launch_bounds__(256, 2)
void gemm_qkv3(const u16* __restrict__ A, const u16* __restrict__ Bt,
               u16* __restrict__ Qo, u16* __restrict__ Ko, u16* __restrict__ Vo) {
  __shared__ u16 lA[3][128 * 32];
  __shared__ u16 lB[3][128 * 32];
  const int tid = threadIdx.x;
  const int lane = tid & 63;
  const int w = tid >> 6;
  const int wr = w >> 1, wc = w & 1;
  const int bm = blockIdx.x * 128;
  const int bn = blockIdx.y * 128;          // 0..6016
  const int fr = lane & 15, fq = lane >> 4;
  const int K = D_;
  const int KT = K >> 5;                    // 64
  f32x4 acc[4][4] = {};

  auto stage = [&](int buf, int kt) {
    const int k0 = kt << 5;
    #pragma unroll
    for (int c = w; c < 8; c += 4) {
      const int r = c * 16 + (lane >> 2);
      const int col = ((lane & 3) ^ ((r >> 1) & 3)) * 8;
      async_copy16(A + (size_t)(bm + r) * K + k0 + col, &lA[buf][c * 512]);
      async_copy16(Bt + (size_t)(bn + r) * K + k0 + col, &lB[buf][c * 512]);
    }
  };

  stage(0, 0);
  stage(1, 1);
  asm volatile("s_waitcnt vmcnt(4)" ::: "memory");
  __builtin_amdgcn_s_barrier();
  asm volatile("" ::: "memory");

  int p = 0, sb = 2;
  #pragma unroll 1
  for (int kt = 0; kt < KT; ++kt) {
    if (kt + 2 < KT) stage(sb, kt + 2);
    bf16x8 af[4], bfr[4];
    #pragma unroll
    for (int i = 0; i < 4; ++i) {
      const int ra = wr * 64 + i * 16 + fr;
      const int rb = wc * 64 + i * 16 + fr;
      af[i]  = *(const bf16x8*)&lA[p][ra * 32 + ((fq ^ ((ra >> 1) & 3)) * 8)];
      bfr[i] = *(const bf16x8*)&lB[p][rb * 32 + ((fq ^ ((rb >> 1) & 3)) * 8)];
    }
    #pragma unroll
    for (int i = 0; i < 4; ++i)
      #pragma unroll
      for (int j = 0; j < 4; ++j)
        acc[i][j] = __builtin_amdgcn_mfma_f32_16x16x32_bf16(af[i], bfr[j], acc[i][j], 0, 0, 0);
    if (kt + 1 < KT) {
      if (kt + 2 < KT) asm volatile("s_waitcnt vmcnt(4)" ::: "memory");
      else             asm volatile("s_waitcnt vmcnt(0)" ::: "memory");
      __builtin_amdgcn_s_barrier();
      asm volatile("" ::: "memory");
    }
    p  = (p == 2) ? 0 : p + 1;
    sb = (sb == 2) ? 0 : sb + 1;
  }
  u16* out = (bn < 2048) ? Qo : (bn < 4096) ? Ko : Vo;
  const int bnl = bn & 2047;
  #pragma unroll
  for (int i = 0; i < 4; ++i)
    #pragma unroll
    for (int j = 0; j < 4; ++j) {
      const int row = bm + wr * 64 + i * 16 + fq * 4;
      const int col = bnl + wc * 64 + j * 16 + fr;
      #pragma unroll
      for (int r = 0; r < 4; ++r)
        out[(size_t)(row + r) * D_ + col] = f2bf(acc[i][j][r]);
    }
}

// ---------------- causal flash attention (no KV-split), swapped-QK softmax + Q-RoPE ----------------
// grid (16, B*H): block x handles q-tiles {x, 31-x} over the FULL causal range
// (66 tile-computes, constant). r18: KV-split dropped (r7 proved it neutral for
// attn; it cost the 12us combine + 17MB partial writes). Normalized O written
// directly. kscale*log2e folded into Q at RoPE time. P stored via 2x ds_write_b64
// (kv slots fq*4..+3 contiguous; bank walk (18*fr)%32 conflict-free).
// Defer-max (T13, THR=12); first tile (t=0) is always fully unmasked.
#define QB 64
#define KB 32
#define PLD 36    // P row stride (72B): [q][kv] layout; b64 reads/writes aligned

__global__ __launch_bounds__(256, 2)
void attn_fwd(const u16* __restrict__ Qg, const u16* __restrict__ Kg,
              const u16* __restrict__ Vg, const float2* __restrict__ tab,
              u16* __restrict__ Og) {
  __shared__ u16 lK[2][KB * HD_];   // linear [kv][hd], source-swizzled content
  __shared__ u16 lV[2][HD_ * 40];   // swizzled V^T
  __shared__ u16 lP[4][16 * PLD];   // per-wave P 16x32, [q][kv]
  const int tid = threadIdx.x;
  const int lane = tid & 63;
  const int w = tid >> 6;
  const int fr = lane & 15, fq = lane >> 4;
  const int xA = blockIdx.x;                 // 0..15
  const int bh = blockIdx.y;
  const size_t base = (size_t)(bh >> 4) * S_ * D_ + (size_t)(bh & 15) * HD_;
  const int qA = xA * QB, qB = (31 - xA) * QB;
  const int ntA = (qA + QB) / KB;            // 2..32
  const int ntB = (qB + QB) / KB;            // 34..64
  const float kscale = 0.08838834764831843f * 1.4426950408889634f; // 1/sqrt(128)*log2e

  // Q fragments for both q-tiles (row=lane&15 -> q, k=(lane>>4)*8+j -> hd)
  bf16x8 qfA[4], qfB[4];
  {
    const u16* qpa = Qg + base + (size_t)(qA + w * 16 + fr) * D_ + fq * 8;
    const u16* qpb = Qg + base + (size_t)(qB + w * 16 + fr) * D_ + fq * 8;
    #pragma unroll
    for (int kk = 0; kk < 4; ++kk) {
      qfA[kk] = *(const bf16x8*)(qpa + kk * 32);
      qfB[kk] = *(const bf16x8*)(qpb + kk * 32);
    }
    // in-register Q-RoPE with kscale fold: d2 = kk*32+fq*8+j pairs with d2+64 (kk+2)
    const float2* tA = &tab[(qA + w * 16 + fr) * 64 + fq * 8];
    const float2* tB = &tab[(qB + w * 16 + fr) * 64 + fq * 8];
    #pragma unroll
    for (int kk = 0; kk < 2; ++kk)
      #pragma unroll
      for (int j = 0; j < 8; ++j) {
        const float2 ca = tA[kk * 32 + j];
        float t1 = bf2f((u16)qfA[kk][j]), t2 = bf2f((u16)qfA[kk + 2][j]);
        qfA[kk][j]     = (short)f2bf((t1 * ca.x - t2 * ca.y) * kscale);
        qfA[kk + 2][j] = (short)f2bf((t1 * ca.y + t2 * ca.x) * kscale);
        const float2 cb = tB[kk * 32 + j];
        t1 = bf2f((u16)qfB[kk][j]); t2 = bf2f((u16)qfB[kk + 2][j]);
        qfB[kk][j]     = (short)f2bf((t1 * cb.x - t2 * cb.y) * kscale);
        qfB[kk + 2][j] = (short)f2bf((t1 * cb.y + t2 * cb.x) * kscale);
      }
  }
  f32x4 oA[8] = {}, oB[8] = {};
  float mAs = -INFINITY, lAs = 0.f, mBs = -INFINITY, lBs = 0.f;

  auto stageK = [&](int buf, int kv0) {
    #pragma unroll
    for (int cc = w; cc < 8; cc += 4) {
      const int row = cc * 4 + (lane >> 4);
      const int slot = (lane & 15) ^ (row & 7);
      async_copy16(Kg + base + (size_t)(kv0 + row) * D_ + slot * 8, &lK[buf][cc * 512]);
    }
  };
  const int srow = tid >> 3, sc0 = (tid & 7) * 16;
  const u32 swz = (u32)((sc0 >> 4) & 7) << 4;
  const u32 rb = (u32)srow * 2;
  u16x8_t rv0, rv1;
  auto loadV = [&](int kv0) {
    const u16* gv = Vg + base + (size_t)(kv0 + srow) * D_ + sc0;
    rv0 = *(const u16x8_t*)gv; rv1 = *(const u16x8_t*)(gv + 8);
  };
  auto writeV = [&](int buf) {
    char* lv = (char*)&lV[buf][0];
    #pragma unroll
    for (int j = 0; j < 8; ++j) {
      *(u16*)(lv + ((((u32)(sc0 + j) * 80) + rb) ^ swz))     = rv0[j];
      *(u16*)(lv + ((((u32)(sc0 + 8 + j) * 80) + rb) ^ swz)) = rv1[j];
    }
  };

  // swapped-layout softmax + defer-max; scores arrive pre-scaled (kscale in Q)
  auto softmax_sw = [&](const f32x4& s0, const f32x4& s1, float& mrow, float& lrow,
                        f32x4* o, int q0t, int kv0) {
    const int qg = q0t + w * 16 + fr;
    const bool notfull = (kv0 + KB - 1 > q0t);
    float v[8];
    #pragma unroll
    for (int r = 0; r < 4; ++r) {
      v[r]     = s0[r];
      v[4 + r] = s1[r];
      if (notfull) {
        if (kv0 + fq * 4 + r > qg)      v[r]     = -INFINITY;
        if (kv0 + 16 + fq * 4 + r > qg) v[4 + r] = -INFINITY;
      }
    }
    float mx = fmaxf(fmaxf(fmaxf(v[0], v[1]), fmaxf(v[2], v[3])),
                     fmaxf(fmaxf(v[4], v[5]), fmaxf(v[6], v[7])));
    mx = fmaxf(mx, __shfl_xor(mx, 16));
    mx = fmaxf(mx, __shfl_xor(mx, 32));
    // T13 defer-max: rescale only when some row's max grew by > 12 log2 units
    const int nogrow = (mx <= mrow + 12.f);
    if (!__all(nogrow)) {
      const float mn = fmaxf(mrow, mx);
      const float al = exp2f(mrow - mn);
      mrow = mn;
      lrow *= al;
      #pragma unroll
      for (int r = 0; r < 4; ++r) {
        const float ab = __shfl(al, fq * 4 + r);
        #pragma unroll
        for (int nb = 0; nb < 8; ++nb) o[nb][r] *= ab;
      }
    }
    float p[8];
    #pragma unroll
    for (int j = 0; j < 8; ++j) p[j] = exp2f(v[j] - mrow);
    float rs = ((p[0] + p[1]) + (p[2] + p[3])) + ((p[4] + p[5]) + (p[6] + p[7]));
    rs += __shfl_xor(rs, 16);
    rs += __shfl_xor(rs, 32);
    lrow += rs;
    // packed P store: 2x ds_write_b64 (kv slots fq*4..+3 and 16+fq*4..+3)
    u32x2 pk0, pk1;
    pk0[0] = (u32)f2bf(p[0]) | ((u32)f2bf(p[1]) << 16);
    pk0[1] = (u32)f2bf(p[2]) | ((u32)f2bf(p[3]) << 16);
    pk1[0] = (u32)f2bf(p[4]) | ((u32)f2bf(p[5]) << 16);
    pk1[1] = (u32)f2bf(p[6]) | ((u32)f2bf(p[7]) << 16);
    *(u32x2*)&lP[w][fr * PLD + fq * 4]      = pk0;
    *(u32x2*)&lP[w][fr * PLD + 16 + fq * 4] = pk1;
  };

  auto pv = [&](f32x4* o, const bf16x8* vf) {
    u32x2 pa0 = *(const u32x2*)&lP[w][fr * PLD + fq * 8];
    u32x2 pa1 = *(const u32x2*)&lP[w][fr * PLD + fq * 8 + 4];
    u32x4 pc; pc[0] = pa0[0]; pc[1] = pa0[1]; pc[2] = pa1[0]; pc[3] = pa1[1];
    const bf16x8 pa = __builtin_bit_cast(bf16x8, pc);
    #pragma unroll
    for (int nb = 0; nb < 8; ++nb)
      o[nb] = __builtin_amdgcn_mfma_f32_16x16x32_bf16(pa, vf[nb], o[nb], 0, 0, 0);
  };

  // prologue: stage tile 0 into buffer 0
  stageK(0, 0);
  loadV(0);
  writeV(0);

  for (int t = 0; t < ntB; ++t) {
    const int kv0 = t * KB;
    const int cur = t & 1, nxt = cur ^ 1;
    __syncthreads();   // drains vmcnt/lgkmcnt: lK[cur] DMA + lV[cur] writes visible
    if (t + 1 < ntB) {
      stageK(nxt, kv0 + KB);   // async DMA, drained by next barrier
      loadV(kv0 + KB);         // regs; consumed by writeV after compute
    }

    const bool doA = (t < ntA);
    // SWAPPED QK^T: mfma(K, Q) -> lane owns one q-row's scores
    f32x4 sA0 = {}, sA1 = {}, sB0 = {}, sB1 = {};
    #pragma unroll
    for (int kk = 0; kk < 4; ++kk) {
      const int sl = ((kk * 4 + fq) ^ (fr & 7)) * 16;
      bf16x8 k0f = *(const bf16x8*)((const char*)&lK[cur][0] + fr * 256 + sl);
      bf16x8 k1f = *(const bf16x8*)((const char*)&lK[cur][0] + (16 + fr) * 256 + sl);
      if (doA) {
        sA0 = __builtin_amdgcn_mfma_f32_16x16x32_bf16(k0f, qfA[kk], sA0, 0, 0, 0);
        sA1 = __builtin_amdgcn_mfma_f32_16x16x32_bf16(k1f, qfA[kk], sA1, 0, 0, 0);
      }
      sB0 = __builtin_amdgcn_mfma_f32_16x16x32_bf16(k0f, qfB[kk], sB0, 0, 0, 0);
      sB1 = __builtin_amdgcn_mfma_f32_16x16x32_bf16(k1f, qfB[kk], sB1, 0, 0, 0);
    }

    bf16x8 vf[8];
    #pragma unroll
    for (int nb = 0; nb < 8; ++nb) {
      const u32 off = (((u32)(nb * 16 + fr) * 80) + (u32)fq * 16) ^ ((u32)nb << 4);
      vf[nb] = *(const bf16x8*)((const char*)&lV[cur][0] + off);
    }

    if (doA) { softmax_sw(sA0, sA1, mAs, lAs, oA, qA, kv0); pv(oA, vf); }
    softmax_sw(sB0, sB1, mBs, lBs, oB, qB, kv0);
    pv(oB, vf);

    if (t + 1 < ntB) writeV(nxt);   // after compute
  }

  // epilogue: normalized O write (inv broadcast from the lane owning each q-row)
  const float invA = 1.0f / lAs;
  const float invB = 1.0f / lBs;
  #pragma unroll
  for (int r = 0; r < 4; ++r) {
    const float ia = __shfl(invA, fq * 4 + r);
    const float ib = __shfl(invB, fq * 4 + r);
    const int rowA = qA + w * 16 + fq * 4 + r;
    const int rowB = qB + w * 16 + fq * 4 + r;
    u16* orA = Og + base + (size_t)rowA * D_;
    u16* orB = Og + base + (size_t)rowB * D_;
    #pragma unroll
    for (int nb = 0; nb < 8; ++nb) {
      orA[nb * 16 + fr] = f2bf(oA[nb][r] * ia);
      orB[nb * 16 + fr] = f2bf(oB[nb][r] * ib);
    }
  }
}

// ---------------- launch ----------------
extern "C" void kernel_launch(void* const* d_in, const int* in_sizes, int n_in,
                              void* d_out, int out_size, void* d_ws, size_t ws_size,
                              hipStream_t stream) {
  const float* x  = (const float*)d_in[0];
  const float* Wq = (const float*)d_in[1];
  const float* Wk = (const float*)d_in[2];
  const float* Wv = (const float*)d_in[3];
  const float* Wo = (const float*)d_in[4];
  const int* pos  = (const int*)d_in[5];

  char* p = (char*)d_ws;
  u16* xb  = (u16*)p; p += (size_t)B_ * S_ * D_ * 2;
  u16* Wqb = (u16*)p; p += (size_t)D_ * D_ * 2;   // Wq/Wk/Wv contiguous -> packed [6144][2048]
  u16* Wkb = (u16*)p; p += (size_t)D_ * D_ * 2;
  u16* Wvb = (u16*)p; p += (size_t)D_ * D_ * 2;
  u16* Wob = (u16*)p; p += (size_t)D_ * D_ * 2;
  u16* Qb  = (u16*)p; p += (size_t)B_ * S_ * D_ * 2;
  u16* Kb  = (u16*)p; p += (size_t)B_ * S_ * D_ * 2;
  u16* Vb  = (u16*)p; p += (size_t)B_ * S_ * D_ * 2;
  float2* tab = (float2*)p; p += (size_t)S_ * 64 * sizeof(float2);
  u16* Ob = Qb;  // attention output overwrites Q in place (each block reads its
                 // own q-tile slices into registers before writing O there)

  cvt_all<<<24576, 256, 0, stream>>>(x, Wq, Wk, Wv, Wo, xb);
  rope_table<<<(S_ * 64) / 256, 256, 0, stream>>>(pos, tab);

  // fused QKV projection: 128x128 tiles (proven optimum), grid (32,48)
  gemm_qkv3<<<dim3(B_ * S_ / 128, 48), 256, 0, stream>>>(xb, Wqb, Qb, Kb, Vb);

  // standalone K-RoPE (Q roped+scaled in-register inside attn)
  rope_k<<<(B_ * S_ * H_ * 16) / 256, 256, 0, stream>>>(Kb, tab);

  // paired-causal flash attention, full range per block (no KV-split/combine)
  attn_fwd<<<dim3(16, B_ * H_), 256, 0, stream>>>(Qb, Kb, Vb, tab, Ob);

  gemm_bt<true><<<dim3(B_ * S_ / 128, D_ / 128), 256, 0, stream>>>(Ob, Wob, (float*)d_out, B_ * S_, D_, D_);
}

// Round 19
// 294.960 us; speedup vs baseline: 3.0824x; 1.0028x over previous
//
#include <hip/hip_runtime.h>
#include <math.h>

// Problem constants
#define B_  2
#define S_  2048
#define D_  2048
#define H_  16
#define HD_ 128

using u16 = unsigned short;
using u32 = unsigned int;
typedef __attribute__((ext_vector_type(4))) float f32x4;
typedef __attribute__((ext_vector_type(8))) short bf16x8;   // 8 bf16 = 4 VGPRs (MFMA A/B frag)
using u16x4_t = __attribute__((ext_vector_type(4))) unsigned short;
using u16x8_t = __attribute__((ext_vector_type(8))) unsigned short;
typedef __attribute__((ext_vector_type(2))) u32 u32x2;
typedef __attribute__((ext_vector_type(4))) u32 u32x4;

__device__ __forceinline__ u16 f2bf(float f) {
  u32 u = __builtin_bit_cast(u32, f);
  u32 r = u + 0x7fffu + ((u >> 16) & 1u);   // RNE
  return (u16)(r >> 16);
}
__device__ __forceinline__ float bf2f(u16 x) {
  u32 u = ((u32)x) << 16;
  return __builtin_bit_cast(float, u);
}
// async global->LDS, 16B per lane; LDS dest = wave-uniform base + lane*16;
// global source address is PER-LANE (enables source-side swizzling).
__device__ __forceinline__ void async_copy16(const u16* g, u16* l) {
  __builtin_amdgcn_global_load_lds((const __attribute__((address_space(1))) u32*)g,
                                   (__attribute__((address_space(3))) u32*)l, 16, 0, 0);
}

// ---------------- fused fp32 -> bf16 convert (x, Wq, Wk, Wv, Wo in one pass) ----------------
__global__ void cvt_all(const float* __restrict__ x, const float* __restrict__ Wq,
                        const float* __restrict__ Wk, const float* __restrict__ Wv,
                        const float* __restrict__ Wo, u16* __restrict__ dst) {
  const int i = (blockIdx.x * blockDim.x + threadIdx.x) * 4;
  if (i >= 25165824) return;
  const float* src;
  int off;
  if (i < (1 << 23)) { src = x; off = i; }
  else {
    const int wi = i - (1 << 23);
    const int which = wi >> 22;
    off = wi & ((1 << 22) - 1);
    src = (which == 0) ? Wq : (which == 1) ? Wk : (which == 2) ? Wv : Wo;
  }
  float4 v = *(const float4*)(src + off);
  u16x4_t o;
  o[0] = f2bf(v.x); o[1] = f2bf(v.y); o[2] = f2bf(v.z); o[3] = f2bf(v.w);
  *(u16x4_t*)(dst + i) = o;
}

// ---------------- RoPE cos/sin table ----------------
__global__ void rope_table(const int* __restrict__ pos, float2* __restrict__ tab) {
  int t = blockIdx.x * blockDim.x + threadIdx.x;  // S*64
  if (t >= S_ * 64) return;
  int s = t >> 6, i = t & 63;
  float freq = expf(-(float)i * (9.210340371976184f / 64.0f));  // theta^{-i/64}
  float ang = (float)pos[s] * freq;
  tab[t] = make_float2(cosf(ang), sinf(ang));
}

// ---------------- K-only RoPE (proven standalone) ----------------
__global__ void rope_k(u16* __restrict__ K, const float2* __restrict__ tab) {
  int t = blockIdx.x * blockDim.x + threadIdx.x;  // B*S*H*16
  int g = t & 15;
  int bsh = t >> 4;
  int h = bsh & (H_ - 1);
  int bs = bsh >> 4;            // b*S + s
  int s = bs & (S_ - 1);
  size_t base = (size_t)bs * D_ + (size_t)h * HD_;
  int d2 = g * 4;
  const float2* tb = &tab[s * 64 + d2];
  float2 cs[4];
  #pragma unroll
  for (int j = 0; j < 4; ++j) cs[j] = tb[j];
  u16x4_t a = *(u16x4_t*)(K + base + d2);
  u16x4_t c = *(u16x4_t*)(K + base + 64 + d2);
  u16x4_t ra, rc;
  #pragma unroll
  for (int j = 0; j < 4; ++j) {
    float t1 = bf2f(a[j]), t2 = bf2f(c[j]);
    ra[j] = f2bf(t1 * cs[j].x - t2 * cs[j].y);
    rc[j] = f2bf(t1 * cs[j].y + t2 * cs[j].x);
  }
  *(u16x4_t*)(K + base + d2) = ra;
  *(u16x4_t*)(K + base + 64 + d2) = rc;
}

// ---------------- GEMM: C = A(MxK) * Bt(NxK)^T (128x128, round-10 proven) ----------------
// r19: launch_bounds (256,3) -> 3 blocks/CU (LDS 48KB allows it; VGPR 68 << 170
// cap). r18's (256,2) was an unintended occupancy cap; m114 shows the m97-class
// structure needs ~3 blocks/CU of cross-block overlap to absorb the barrier drain.
template <bool F32OUT>
__global__ __launch_bounds__(256, 3)
void gemm_bt(const u16* __restrict__ A, const u16* __restrict__ Bt,
             void* __restrict__ Cout, int M, int N, int K) {
  __shared__ u16 lA[3][128 * 32];
  __shared__ u16 lB[3][128 * 32];
  const int tid = threadIdx.x;
  const int lane = tid & 63;
  const int w = tid >> 6;            // wave 0..3
  const int wr = w >> 1, wc = w & 1; // 2x2 waves of 64x64
  const int bm = blockIdx.x * 128;
  const int bn = blockIdx.y * 128;
  const int fr = lane & 15, fq = lane >> 4;
  const int KT = K >> 5;
  f32x4 acc[4][4] = {};

  auto stage = [&](int buf, int kt) {
    const int k0 = kt << 5;
    #pragma unroll
    for (int c = w; c < 8; c += 4) {
      const int r = c * 16 + (lane >> 2);
      const int col = ((lane & 3) ^ ((r >> 1) & 3)) * 8;   // pre-swizzled source slot
      async_copy16(A + (size_t)(bm + r) * K + k0 + col, &lA[buf][c * 512]);
      async_copy16(Bt + (size_t)(bn + r) * K + k0 + col, &lB[buf][c * 512]);
    }
  };

  stage(0, 0);
  stage(1, 1);
  asm volatile("s_waitcnt vmcnt(4)" ::: "memory");   // tile 0 landed; tile 1 in flight
  __builtin_amdgcn_s_barrier();
  asm volatile("" ::: "memory");

  int p = 0, sb = 2;
  #pragma unroll 1
  for (int kt = 0; kt < KT; ++kt) {
    if (kt + 2 < KT) stage(sb, kt + 2);
    bf16x8 af[4], bfr[4];
    #pragma unroll
    for (int i = 0; i < 4; ++i) {
      const int ra = wr * 64 + i * 16 + fr;
      const int rb = wc * 64 + i * 16 + fr;
      af[i]  = *(const bf16x8*)&lA[p][ra * 32 + ((fq ^ ((ra >> 1) & 3)) * 8)];
      bfr[i] = *(const bf16x8*)&lB[p][rb * 32 + ((fq ^ ((rb >> 1) & 3)) * 8)];
    }
    #pragma unroll
    for (int i = 0; i < 4; ++i)
      #pragma unroll
      for (int j = 0; j < 4; ++j)
        acc[i][j] = __builtin_amdgcn_mfma_f32_16x16x32_bf16(af[i], bfr[j], acc[i][j], 0, 0, 0);
    if (kt + 1 < KT) {
      if (kt + 2 < KT) asm volatile("s_waitcnt vmcnt(4)" ::: "memory");  // kt+1 landed
      else             asm volatile("s_waitcnt vmcnt(0)" ::: "memory");  // tail drain
      __builtin_amdgcn_s_barrier();
      asm volatile("" ::: "memory");
    }
    p  = (p == 2) ? 0 : p + 1;
    sb = (sb == 2) ? 0 : sb + 1;
  }
  // C/D layout: col = lane&15, row = (lane>>4)*4 + reg  [m89/m91 verified]
  #pragma unroll
  for (int i = 0; i < 4; ++i)
    #pragma unroll
    for (int j = 0; j < 4; ++j) {
      const int row = bm + wr * 64 + i * 16 + fq * 4;
      const int col = bn + wc * 64 + j * 16 + fr;
      #pragma unroll
      for (int r = 0; r < 4; ++r) {
        const float v = acc[i][j][r];
        if (F32OUT) ((float*)Cout)[(size_t)(row + r) * N + col] = v;
        else        ((u16*)Cout)[(size_t)(row + r) * N + col] = f2bf(v);
      }
    }
}

// ---------------- fused QKV GEMM: Bt packed [6144][2048] (Wq;Wk;Wv) ----------------
// r19: launch_bounds (256,3) -> 3 blocks/CU (see gemm_bt comment).
__global__ __launch_bounds__(256, 3)
void gemm_qkv3(const u16* __restrict__ A, const u16* __restrict__ Bt,
               u16* __restrict__ Qo, u16* __restrict__ Ko, u16* __restrict__ Vo) {
  __shared__ u16 lA[3][128 * 32];
  __shared__ u16 lB[3][128 * 32];
  const int tid = threadIdx.x;
  const int lane = tid & 63;
  const int w = tid >> 6;
  const int wr = w >> 1, wc = w & 1;
  const int bm = blockIdx.x * 128;
  const int bn = blockIdx.y * 128;          // 0..6016
  const int fr = lane & 15, fq = lane >> 4;
  const int K = D_;
  const int KT = K >> 5;                    // 64
  f32x4 acc[4][4] = {};

  auto stage = [&](int buf, int kt) {
    const int k0 = kt << 5;
    #pragma unroll
    for (int c = w; c < 8; c += 4) {
      const int r = c * 16 + (lane >> 2);
      const int col = ((lane & 3) ^ ((r >> 1) & 3)) * 8;
      async_copy16(A + (size_t)(bm + r) * K + k0 + col, &lA[buf][c * 512]);
      async_copy16(Bt + (size_t)(bn + r) * K + k0 + col, &lB[buf][c * 512]);
    }
  };

  stage(0, 0);
  stage(1, 1);
  asm volatile("s_waitcnt vmcnt(4)" ::: "memory");
  __builtin_amdgcn_s_barrier();
  asm volatile("" ::: "memory");

  int p = 0, sb = 2;
  #pragma unroll 1
  for (int kt = 0; kt < KT; ++kt) {
    if (kt + 2 < KT) stage(sb, kt + 2);
    bf16x8 af[4], bfr[4];
    #pragma unroll
    for (int i = 0; i < 4; ++i) {
      const int ra = wr * 64 + i * 16 + fr;
      const int rb = wc * 64 + i * 16 + fr;
      af[i]  = *(const bf16x8*)&lA[p][ra * 32 + ((fq ^ ((ra >> 1) & 3)) * 8)];
      bfr[i] = *(const bf16x8*)&lB[p][rb * 32 + ((fq ^ ((rb >> 1) & 3)) * 8)];
    }
    #pragma unroll
    for (int i = 0; i < 4; ++i)
      #pragma unroll
      for (int j = 0; j < 4; ++j)
        acc[i][j] = __builtin_amdgcn_mfma_f32_16x16x32_bf16(af[i], bfr[j], acc[i][j], 0, 0, 0);
    if (kt + 1 < KT) {
      if (kt + 2 < KT) asm volatile("s_waitcnt vmcnt(4)" ::: "memory");
      else             asm volatile("s_waitcnt vmcnt(0)" ::: "memory");
      __builtin_amdgcn_s_barrier();
      asm volatile("" ::: "memory");
    }
    p  = (p == 2) ? 0 : p + 1;
    sb = (sb == 2) ? 0 : sb + 1;
  }
  u16* out = (bn < 2048) ? Qo : (bn < 4096) ? Ko : Vo;
  const int bnl = bn & 2047;
  #pragma unroll
  for (int i = 0; i < 4; ++i)
    #pragma unroll
    for (int j = 0; j < 4; ++j) {
      const int row = bm + wr * 64 + i * 16 + fq * 4;
      const int col = bnl + wc * 64 + j * 16 + fr;
      #pragma unroll
      for (int r = 0; r < 4; ++r)
        out[(size_t)(row + r) * D_ + col] = f2bf(acc[i][j][r]);
    }
}

// ---------------- causal flash attention (no KV-split), swapped-QK softmax + Q-RoPE ----------------
// grid (16, B*H): block x handles q-tiles {x, 31-x} over the FULL causal range
// (66 tile-computes, constant). Normalized O written directly. kscale*log2e
// folded into Q at RoPE time. P stored via 2x ds_write_b64. Defer-max (T13).
#define QB 64
#define KB 32
#define PLD 36    // P row stride (72B): [q][kv] layout; b64 reads/writes aligned

__global__ __launch_bounds__(256, 2)
void attn_fwd(const u16* __restrict__ Qg, const u16* __restrict__ Kg,
              const u16* __restrict__ Vg, const float2* __restrict__ tab,
              u16* __restrict__ Og) {
  __shared__ u16 lK[2][KB * HD_];   // linear [kv][hd], source-swizzled content
  __shared__ u16 lV[2][HD_ * 40];   // swizzled V^T
  __shared__ u16 lP[4][16 * PLD];   // per-wave P 16x32, [q][kv]
  const int tid = threadIdx.x;
  const int lane = tid & 63;
  const int w = tid >> 6;
  const int fr = lane & 15, fq = lane >> 4;
  const int xA = blockIdx.x;                 // 0..15
  const int bh = blockIdx.y;
  const size_t base = (size_t)(bh >> 4) * S_ * D_ + (size_t)(bh & 15) * HD_;
  const int qA = xA * QB, qB = (31 - xA) * QB;
  const int ntA = (qA + QB) / KB;            // 2..32
  const int ntB = (qB + QB) / KB;            // 34..64
  const float kscale = 0.08838834764831843f * 1.4426950408889634f; // 1/sqrt(128)*log2e

  // Q fragments for both q-tiles (row=lane&15 -> q, k=(lane>>4)*8+j -> hd)
  bf16x8 qfA[4], qfB[4];
  {
    const u16* qpa = Qg + base + (size_t)(qA + w * 16 + fr) * D_ + fq * 8;
    const u16* qpb = Qg + base + (size_t)(qB + w * 16 + fr) * D_ + fq * 8;
    #pragma unroll
    for (int kk = 0; kk < 4; ++kk) {
      qfA[kk] = *(const bf16x8*)(qpa + kk * 32);
      qfB[kk] = *(const bf16x8*)(qpb + kk * 32);
    }
    // in-register Q-RoPE with kscale fold: d2 = kk*32+fq*8+j pairs with d2+64 (kk+2)
    const float2* tA = &tab[(qA + w * 16 + fr) * 64 + fq * 8];
    const float2* tB = &tab[(qB + w * 16 + fr) * 64 + fq * 8];
    #pragma unroll
    for (int kk = 0; kk < 2; ++kk)
      #pragma unroll
      for (int j = 0; j < 8; ++j) {
        const float2 ca = tA[kk * 32 + j];
        float t1 = bf2f((u16)qfA[kk][j]), t2 = bf2f((u16)qfA[kk + 2][j]);
        qfA[kk][j]     = (short)f2bf((t1 * ca.x - t2 * ca.y) * kscale);
        qfA[kk + 2][j] = (short)f2bf((t1 * ca.y + t2 * ca.x) * kscale);
        const float2 cb = tB[kk * 32 + j];
        t1 = bf2f((u16)qfB[kk][j]); t2 = bf2f((u16)qfB[kk + 2][j]);
        qfB[kk][j]     = (short)f2bf((t1 * cb.x - t2 * cb.y) * kscale);
        qfB[kk + 2][j] = (short)f2bf((t1 * cb.y + t2 * cb.x) * kscale);
      }
  }
  f32x4 oA[8] = {}, oB[8] = {};
  float mAs = -INFINITY, lAs = 0.f, mBs = -INFINITY, lBs = 0.f;

  auto stageK = [&](int buf, int kv0) {
    #pragma unroll
    for (int cc = w; cc < 8; cc += 4) {
      const int row = cc * 4 + (lane >> 4);
      const int slot = (lane & 15) ^ (row & 7);
      async_copy16(Kg + base + (size_t)(kv0 + row) * D_ + slot * 8, &lK[buf][cc * 512]);
    }
  };
  const int srow = tid >> 3, sc0 = (tid & 7) * 16;
  const u32 swz = (u32)((sc0 >> 4) & 7) << 4;
  const u32 rb = (u32)srow * 2;
  u16x8_t rv0, rv1;
  auto loadV = [&](int kv0) {
    const u16* gv = Vg + base + (size_t)(kv0 + srow) * D_ + sc0;
    rv0 = *(const u16x8_t*)gv; rv1 = *(const u16x8_t*)(gv + 8);
  };
  auto writeV = [&](int buf) {
    char* lv = (char*)&lV[buf][0];
    #pragma unroll
    for (int j = 0; j < 8; ++j) {
      *(u16*)(lv + ((((u32)(sc0 + j) * 80) + rb) ^ swz))     = rv0[j];
      *(u16*)(lv + ((((u32)(sc0 + 8 + j) * 80) + rb) ^ swz)) = rv1[j];
    }
  };

  // swapped-layout softmax + defer-max; scores arrive pre-scaled (kscale in Q)
  auto softmax_sw = [&](const f32x4& s0, const f32x4& s1, float& mrow, float& lrow,
                        f32x4* o, int q0t, int kv0) {
    const int qg = q0t + w * 16 + fr;
    const bool notfull = (kv0 + KB - 1 > q0t);
    float v[8];
    #pragma unroll
    for (int r = 0; r < 4; ++r) {
      v[r]     = s0[r];
      v[4 + r] = s1[r];
      if (notfull) {
        if (kv0 + fq * 4 + r > qg)      v[r]     = -INFINITY;
        if (kv0 + 16 + fq * 4 + r > qg) v[4 + r] = -INFINITY;
      }
    }
    float mx = fmaxf(fmaxf(fmaxf(v[0], v[1]), fmaxf(v[2], v[3])),
                     fmaxf(fmaxf(v[4], v[5]), fmaxf(v[6], v[7])));
    mx = fmaxf(mx, __shfl_xor(mx, 16));
    mx = fmaxf(mx, __shfl_xor(mx, 32));
    // T13 defer-max: rescale only when some row's max grew by > 12 log2 units
    const int nogrow = (mx <= mrow + 12.f);
    if (!__all(nogrow)) {
      const float mn = fmaxf(mrow, mx);
      const float al = exp2f(mrow - mn);
      mrow = mn;
      lrow *= al;
      #pragma unroll
      for (int r = 0; r < 4; ++r) {
        const float ab = __shfl(al, fq * 4 + r);
        #pragma unroll
        for (int nb = 0; nb < 8; ++nb) o[nb][r] *= ab;
      }
    }
    float p[8];
    #pragma unroll
    for (int j = 0; j < 8; ++j) p[j] = exp2f(v[j] - mrow);
    float rs = ((p[0] + p[1]) + (p[2] + p[3])) + ((p[4] + p[5]) + (p[6] + p[7]));
    rs += __shfl_xor(rs, 16);
    rs += __shfl_xor(rs, 32);
    lrow += rs;
    // packed P store: 2x ds_write_b64 (kv slots fq*4..+3 and 16+fq*4..+3)
    u32x2 pk0, pk1;
    pk0[0] = (u32)f2bf(p[0]) | ((u32)f2bf(p[1]) << 16);
    pk0[1] = (u32)f2bf(p[2]) | ((u32)f2bf(p[3]) << 16);
    pk1[0] = (u32)f2bf(p[4]) | ((u32)f2bf(p[5]) << 16);
    pk1[1] = (u32)f2bf(p[6]) | ((u32)f2bf(p[7]) << 16);
    *(u32x2*)&lP[w][fr * PLD + fq * 4]      = pk0;
    *(u32x2*)&lP[w][fr * PLD + 16 + fq * 4] = pk1;
  };

  auto pv = [&](f32x4* o, const bf16x8* vf) {
    u32x2 pa0 = *(const u32x2*)&lP[w][fr * PLD + fq * 8];
    u32x2 pa1 = *(const u32x2*)&lP[w][fr * PLD + fq * 8 + 4];
    u32x4 pc; pc[0] = pa0[0]; pc[1] = pa0[1]; pc[2] = pa1[0]; pc[3] = pa1[1];
    const bf16x8 pa = __builtin_bit_cast(bf16x8, pc);
    #pragma unroll
    for (int nb = 0; nb < 8; ++nb)
      o[nb] = __builtin_amdgcn_mfma_f32_16x16x32_bf16(pa, vf[nb], o[nb], 0, 0, 0);
  };

  // prologue: stage tile 0 into buffer 0
  stageK(0, 0);
  loadV(0);
  writeV(0);

  for (int t = 0; t < ntB; ++t) {
    const int kv0 = t * KB;
    const int cur = t & 1, nxt = cur ^ 1;
    __syncthreads();   // drains vmcnt/lgkmcnt: lK[cur] DMA + lV[cur] writes visible
    if (t + 1 < ntB) {
      stageK(nxt, kv0 + KB);   // async DMA, drained by next barrier
      loadV(kv0 + KB);         // regs; consumed by writeV after compute
    }

    const bool doA = (t < ntA);
    // SWAPPED QK^T: mfma(K, Q) -> lane owns one q-row's scores
    f32x4 sA0 = {}, sA1 = {}, sB0 = {}, sB1 = {};
    #pragma unroll
    for (int kk = 0; kk < 4; ++kk) {
      const int sl = ((kk * 4 + fq) ^ (fr & 7)) * 16;
      bf16x8 k0f = *(const bf16x8*)((const char*)&lK[cur][0] + fr * 256 + sl);
      bf16x8 k1f = *(const bf16x8*)((const char*)&lK[cur][0] + (16 + fr) * 256 + sl);
      if (doA) {
        sA0 = __builtin_amdgcn_mfma_f32_16x16x32_bf16(k0f, qfA[kk], sA0, 0, 0, 0);
        sA1 = __builtin_amdgcn_mfma_f32_16x16x32_bf16(k1f, qfA[kk], sA1, 0, 0, 0);
      }
      sB0 = __builtin_amdgcn_mfma_f32_16x16x32_bf16(k0f, qfB[kk], sB0, 0, 0, 0);
      sB1 = __builtin_amdgcn_mfma_f32_16x16x32_bf16(k1f, qfB[kk], sB1, 0, 0, 0);
    }

    bf16x8 vf[8];
    #pragma unroll
    for (int nb = 0; nb < 8; ++nb) {
      const u32 off = (((u32)(nb * 16 + fr) * 80) + (u32)fq * 16) ^ ((u32)nb << 4);
      vf[nb] = *(const bf16x8*)((const char*)&lV[cur][0] + off);
    }

    if (doA) { softmax_sw(sA0, sA1, mAs, lAs, oA, qA, kv0); pv(oA, vf); }
    softmax_sw(sB0, sB1, mBs, lBs, oB, qB, kv0);
    pv(oB, vf);

    if (t + 1 < ntB) writeV(nxt);   // after compute
  }

  // epilogue: normalized O write (inv broadcast from the lane owning each q-row)
  const float invA = 1.0f / lAs;
  const float invB = 1.0f / lBs;
  #pragma unroll
  for (int r = 0; r < 4; ++r) {
    const float ia = __shfl(invA, fq * 4 + r);
    const float ib = __shfl(invB, fq * 4 + r);
    const int rowA = qA + w * 16 + fq * 4 + r;
    const int rowB = qB + w * 16 + fq * 4 + r;
    u16* orA = Og + base + (size_t)rowA * D_;
    u16* orB = Og + base + (size_t)rowB * D_;
    #pragma unroll
    for (int nb = 0; nb < 8; ++nb) {
      orA[nb * 16 + fr] = f2bf(oA[nb][r] * ia);
      orB[nb * 16 + fr] = f2bf(oB[nb][r] * ib);
    }
  }
}

// ---------------- launch ----------------
extern "C" void kernel_launch(void* const* d_in, const int* in_sizes, int n_in,
                              void* d_out, int out_size, void* d_ws, size_t ws_size,
                              hipStream_t stream) {
  const float* x  = (const float*)d_in[0];
  const float* Wq = (const float*)d_in[1];
  const float* Wk = (const float*)d_in[2];
  const float* Wv = (const float*)d_in[3];
  const float* Wo = (const float*)d_in[4];
  const int* pos  = (const int*)d_in[5];

  char* p = (char*)d_ws;
  u16* xb  = (u16*)p; p += (size_t)B_ * S_ * D_ * 2;
  u16* Wqb = (u16*)p; p += (size_t)D_ * D_ * 2;   // Wq/Wk/Wv contiguous -> packed [6144][2048]
  u16* Wkb = (u16*)p; p += (size_t)D_ * D_ * 2;
  u16* Wvb = (u16*)p; p += (size_t)D_ * D_ * 2;
  u16* Wob = (u16*)p; p += (size_t)D_ * D_ * 2;
  u16* Qb  = (u16*)p; p += (size_t)B_ * S_ * D_ * 2;
  u16* Kb  = (u16*)p; p += (size_t)B_ * S_ * D_ * 2;
  u16* Vb  = (u16*)p; p += (size_t)B_ * S_ * D_ * 2;
  float2* tab = (float2*)p; p += (size_t)S_ * 64 * sizeof(float2);
  u16* Ob = Qb;  // attention output overwrites Q in place (each block reads its
                 // own q-tile slices into registers before writing O there)

  cvt_all<<<24576, 256, 0, stream>>>(x, Wq, Wk, Wv, Wo, xb);
  rope_table<<<(S_ * 64) / 256, 256, 0, stream>>>(pos, tab);

  // fused QKV projection: 128x128 tiles, grid (32,48)
  gemm_qkv3<<<dim3(B_ * S_ / 128, 48), 256, 0, stream>>>(xb, Wqb, Qb, Kb, Vb);

  // standalone K-RoPE (Q roped+scaled in-register inside attn)
  rope_k<<<(B_ * S_ * H_ * 16) / 256, 256, 0, stream>>>(Kb, tab);

  // paired-causal flash attention, full range per block (no KV-split/combine)
  attn_fwd<<<dim3(16, B_ * H_), 256, 0, stream>>>(Qb, Kb, Vb, tab, Ob);

  gemm_bt<true><<<dim3(B_ * S_ / 128, D_ / 128), 256, 0, stream>>>(Ob, Wob, (float*)d_out, B_ * S_, D_, D_);
}